// Round 2
// baseline (357.783 us; speedup 1.0000x reference)
//
#include <hip/hip_runtime.h>
#include <hip/hip_bf16.h>
#include <stdint.h>

#define B_ 4
#define L_ 4096
#define D_ 1024
#define H_ 16
#define E_ 64
#define M_ (B_*L_)       // 16384 rows
#define N1_ (3*D_)       // 3072
#define CHK 128
#define NC (L_/CHK)      // 32
#define BH (B_*H_)       // 64

#define EPS_FEAT 1.0001f
#define EPS_DEN 1e-6f

typedef __attribute__((ext_vector_type(4))) float f32x4;
typedef __attribute__((ext_vector_type(8))) short bf16x8;

__device__ __forceinline__ unsigned short f2bf(float x) {
    union { float f; unsigned int u; } v; v.f = x;
    unsigned int r = v.u + 0x7FFFu + ((v.u >> 16) & 1u);
    return (unsigned short)(r >> 16);
}

// ---------------- prep kernels ----------------

__global__ __launch_bounds__(256) void cvt_x(const float* __restrict__ x,
                                             unsigned short* __restrict__ xb) {
    int i4 = blockIdx.x * 256 + threadIdx.x;      // float4 index
    float4 v = ((const float4*)x)[i4];
    unsigned int lo = (unsigned int)f2bf(v.x) | ((unsigned int)f2bf(v.y) << 16);
    unsigned int hi = (unsigned int)f2bf(v.z) | ((unsigned int)f2bf(v.w) << 16);
    ((uint2*)xb)[i4] = make_uint2(lo, hi);
}

// W (K,N) f32 -> WT (N,K) bf16
__global__ __launch_bounds__(256) void transp_w(const float* __restrict__ W,
                                                unsigned short* __restrict__ WT,
                                                int K, int N) {
    __shared__ float tile[32][33];
    int kb = blockIdx.y * 32, nb = blockIdx.x * 32;
    int tx = threadIdx.x & 31, ty = threadIdx.x >> 5;   // ty 0..7
#pragma unroll
    for (int j = 0; j < 4; ++j)
        tile[ty + 8*j][tx] = W[(size_t)(kb + ty + 8*j) * N + nb + tx];
    __syncthreads();
#pragma unroll
    for (int j = 0; j < 4; ++j) {
        int nl = ty + 8*j;
        WT[(size_t)(nb + nl) * K + kb + tx] = f2bf(tile[tx][nl]);
    }
}

// ---------------- GEMM (A bf16 MxK, BT bf16 NxK) ----------------
// MODE 0: qkv epilogue (feature map, split into q/k/v buffers (B,H,L,E))
// MODE 1: plain f32 output + bias

template<int MODE>
__global__ __launch_bounds__(256) void gemm_bt(
    const unsigned short* __restrict__ A,
    const unsigned short* __restrict__ BT,
    const float* __restrict__ bias,
    int Kdim, int Ndim,
    float* __restrict__ outF,
    unsigned short* __restrict__ qf,
    unsigned short* __restrict__ kf,
    unsigned short* __restrict__ vf)
{
    constexpr int LDT = 40;   // padded stride (elems), 16B aligned rows, 2-way banks
    __shared__ unsigned short As[128 * LDT];
    __shared__ unsigned short Bs[128 * LDT];

    int t = threadIdx.x, lane = t & 63, w = t >> 6;
    int wm = w >> 1, wn = w & 1;
    int m0 = blockIdx.y * 128, n0 = blockIdx.x * 128;
    int lr = lane & 15, lg = lane >> 4;

    f32x4 acc[4][4] = {};

    for (int kt = 0; kt < Kdim; kt += 32) {
#pragma unroll
        for (int it = 0; it < 2; ++it) {
            int s = it * 256 + t;            // 0..511
            int row = s >> 2, e0 = (s & 3) << 3;
            uint4 av = *(const uint4*)(A  + (size_t)(m0 + row) * Kdim + kt + e0);
            uint4 bv = *(const uint4*)(BT + (size_t)(n0 + row) * Kdim + kt + e0);
            *(uint4*)&As[row * LDT + e0] = av;
            *(uint4*)&Bs[row * LDT + e0] = bv;
        }
        __syncthreads();
        bf16x8 af[4], bfr[4];
#pragma unroll
        for (int m = 0; m < 4; ++m)
            af[m] = *(const bf16x8*)&As[(wm*64 + m*16 + lr) * LDT + lg*8];
#pragma unroll
        for (int n = 0; n < 4; ++n)
            bfr[n] = *(const bf16x8*)&Bs[(wn*64 + n*16 + lr) * LDT + lg*8];
#pragma unroll
        for (int m = 0; m < 4; ++m)
#pragma unroll
            for (int n = 0; n < 4; ++n)
                acc[m][n] = __builtin_amdgcn_mfma_f32_16x16x32_bf16(af[m], bfr[n], acc[m][n], 0, 0, 0);
        __syncthreads();
    }

    // epilogue. D element: row = m0+wm*64+m*16+lg*4+q, col = n0+wn*64+n*16+lr
#pragma unroll
    for (int n = 0; n < 4; ++n) {
        int c = n0 + wn*64 + n*16 + lr;
        float bv = bias[c];
#pragma unroll
        for (int m = 0; m < 4; ++m) {
#pragma unroll
            for (int q = 0; q < 4; ++q) {
                int r = m0 + wm*64 + m*16 + lg*4 + q;
                float val = acc[m][n][q] + bv;
                if (MODE == 0) {
                    int b = r >> 12, l = r & 4095;
                    int h = (c & 1023) >> 6, e = c & 63;
                    size_t dst = (((size_t)(b * H_ + h)) * L_ + l) * E_ + e;
                    if (c < D_) {
                        float xq = val * 0.125f;                       // E^-0.5
                        float fq = xq > 0.f ? xq : __expf(xq) - 1.f;   // elu
                        qf[dst] = f2bf(fq + EPS_FEAT);
                    } else if (c < 2 * D_) {
                        float fk = val > 0.f ? val : __expf(val) - 1.f;
                        kf[dst] = f2bf(fk + EPS_FEAT);
                    } else {
                        vf[dst] = f2bf(val);
                    }
                } else {
                    outF[(size_t)r * Ndim + c] = val;
                }
            }
        }
    }
}

// ---------------- chunk KV: KV_c[e][f] = sum_l K[l][e] V[l][f], ksum_c[e] ----------------

__global__ __launch_bounds__(256) void chunk_kv(
    const unsigned short* __restrict__ kf, const unsigned short* __restrict__ vf,
    float* __restrict__ kvout, float* __restrict__ ksout)
{
    constexpr int LDK = 136;                 // 128 + 8 pad
    __shared__ unsigned short Kt[64 * LDK];  // K^T : [e][l]
    __shared__ unsigned short Vt[80 * LDK];  // V^T : [f][l], row 64 = ones (ksum trick)

    int t = threadIdx.x, lane = t & 63, w = t >> 6;
    int bid = blockIdx.x;                    // bh*NC + c
    const unsigned short* kp = kf + (size_t)bid * CHK * E_;
    const unsigned short* vp = vf + (size_t)bid * CHK * E_;

#pragma unroll
    for (int it = 0; it < 4; ++it) {
        int s = it * 256 + t;                // 0..1023  (16B granules of 128x64)
        int rl = s >> 3, e0 = (s & 7) << 3;
        uint4 kv8 = *(const uint4*)(kp + s * 8);
        uint4 vv8 = *(const uint4*)(vp + s * 8);
        unsigned int kw[4] = {kv8.x, kv8.y, kv8.z, kv8.w};
        unsigned int vw[4] = {vv8.x, vv8.y, vv8.z, vv8.w};
#pragma unroll
        for (int jw = 0; jw < 4; ++jw) {
            Kt[(e0 + 2*jw    ) * LDK + rl] = (unsigned short)(kw[jw] & 0xFFFF);
            Kt[(e0 + 2*jw + 1) * LDK + rl] = (unsigned short)(kw[jw] >> 16);
            Vt[(e0 + 2*jw    ) * LDK + rl] = (unsigned short)(vw[jw] & 0xFFFF);
            Vt[(e0 + 2*jw + 1) * LDK + rl] = (unsigned short)(vw[jw] >> 16);
        }
    }
    if (t < 128) Vt[64 * LDK + t] = 0x3F80;  // bf16 1.0
    for (int i = t; i < 15 * LDK; i += 256) Vt[65 * LDK + i] = 0;
    __syncthreads();

    int lr = lane & 15, lg = lane >> 4;
    f32x4 acc[5] = {};
#pragma unroll
    for (int ks = 0; ks < 4; ++ks) {
        bf16x8 a = *(const bf16x8*)&Kt[(w*16 + lr) * LDK + ks*32 + lg*8];
#pragma unroll
        for (int n = 0; n < 5; ++n) {
            bf16x8 b = *(const bf16x8*)&Vt[(n*16 + lr) * LDK + ks*32 + lg*8];
            acc[n] = __builtin_amdgcn_mfma_f32_16x16x32_bf16(a, b, acc[n], 0, 0, 0);
        }
    }
    float* kvo = kvout + (size_t)bid * E_ * E_;
#pragma unroll
    for (int n = 0; n < 4; ++n)
#pragma unroll
        for (int q = 0; q < 4; ++q) {
            int e = w*16 + lg*4 + q, f = n*16 + lr;
            kvo[e * 64 + f] = acc[n][q];
        }
    if (lr == 0) {
#pragma unroll
        for (int q = 0; q < 4; ++q) {
            int e = w*16 + lg*4 + q;
            ksout[(size_t)bid * 64 + e] = acc[4][q];
        }
    }
}

// ---------------- exclusive prefix over chunks (per bh) ----------------

__global__ __launch_bounds__(256) void prefix_kv(float* __restrict__ kv, float* __restrict__ ks) {
    int bh = blockIdx.x, t = threadIdx.x;
    float st[16];
#pragma unroll
    for (int j = 0; j < 16; ++j) st[j] = 0.f;
    for (int c = 0; c < NC; ++c) {
        float* p = kv + ((size_t)bh * NC + c) * 4096;
#pragma unroll
        for (int j = 0; j < 16; ++j) {
            float tmp = p[j * 256 + t];
            p[j * 256 + t] = st[j];
            st[j] += tmp;
        }
    }
    if (t < 64) {
        float s0 = 0.f;
        for (int c = 0; c < NC; ++c) {
            float* p = ks + ((size_t)bh * NC + c) * 64;
            float tmp = p[t]; p[t] = s0; s0 += tmp;
        }
    }
}

// ---------------- attention output per (bh, chunk) ----------------

__global__ __launch_bounds__(256) void attn_out(
    const unsigned short* __restrict__ qf, const unsigned short* __restrict__ kf,
    const unsigned short* __restrict__ vf, const float* __restrict__ kvst,
    const float* __restrict__ ksst, unsigned short* __restrict__ attn)
{
    constexpr int LQ = 72;    // Q/K stride (64+8)
    constexpr int LV = 136;   // Vt & S stride (128+8)
    constexpr int LKV = 72;   // KVt stride (64+8)
    __shared__ unsigned short Qs[128 * LQ];
    __shared__ unsigned short Ks[128 * LQ];
    __shared__ unsigned short Vt[80 * LV];    // row 64 = ones
    __shared__ unsigned short KVt[80 * LKV];  // row 64 = ksum
    __shared__ unsigned short Ss[128 * LV];

    int t = threadIdx.x, lane = t & 63, w = t >> 6;
    int bid = blockIdx.x;
    int bh = bid >> 5, c = bid & 31;
    const unsigned short* qp = qf + (size_t)bid * CHK * E_;
    const unsigned short* kp = kf + (size_t)bid * CHK * E_;
    const unsigned short* vp = vf + (size_t)bid * CHK * E_;

#pragma unroll
    for (int it = 0; it < 4; ++it) {
        int s = it * 256 + t;
        int r = s >> 3, e0 = (s & 7) << 3;
        uint4 qv = *(const uint4*)(qp + s * 8);
        uint4 kv = *(const uint4*)(kp + s * 8);
        uint4 vv = *(const uint4*)(vp + s * 8);
        *(uint4*)&Qs[r * LQ + e0] = qv;
        *(uint4*)&Ks[r * LQ + e0] = kv;
        unsigned int vw[4] = {vv.x, vv.y, vv.z, vv.w};
#pragma unroll
        for (int jw = 0; jw < 4; ++jw) {
            Vt[(e0 + 2*jw    ) * LV + r] = (unsigned short)(vw[jw] & 0xFFFF);
            Vt[(e0 + 2*jw + 1) * LV + r] = (unsigned short)(vw[jw] >> 16);
        }
    }
    const float* kvp = kvst + (size_t)bid * 4096;
#pragma unroll
    for (int it = 0; it < 16; ++it) {
        int idx = it * 256 + t;
        int e = idx >> 6, f = idx & 63;
        KVt[f * LKV + e] = f2bf(kvp[idx]);
    }
    if (t < 64)  KVt[64 * LKV + t] = f2bf(ksst[(size_t)bid * 64 + t]);
    if (t < 128) Vt[64 * LV + t] = 0x3F80;
    for (int i = t; i < 15 * LV;  i += 256) Vt[65 * LV  + i] = 0;
    for (int i = t; i < 15 * LKV; i += 256) KVt[65 * LKV + i] = 0;
    __syncthreads();

    int lr = lane & 15, lg = lane >> 4;

    // S-phase: wave w owns rows [w*32, w*32+32)
#pragma unroll
    for (int m = 0; m < 2; ++m) {
        int rbase = w * 32 + m * 16;
        bf16x8 aq0 = *(const bf16x8*)&Qs[(rbase + lr) * LQ + lg*8];
        bf16x8 aq1 = *(const bf16x8*)&Qs[(rbase + lr) * LQ + 32 + lg*8];
        int jmax = 2 * w + m;
        for (int jb = 0; jb < 8; ++jb) {
            if (jb <= jmax) {
                f32x4 sacc = {};
                bf16x8 b0 = *(const bf16x8*)&Ks[(jb*16 + lr) * LQ + lg*8];
                bf16x8 b1 = *(const bf16x8*)&Ks[(jb*16 + lr) * LQ + 32 + lg*8];
                sacc = __builtin_amdgcn_mfma_f32_16x16x32_bf16(aq0, b0, sacc, 0, 0, 0);
                sacc = __builtin_amdgcn_mfma_f32_16x16x32_bf16(aq1, b1, sacc, 0, 0, 0);
#pragma unroll
                for (int q = 0; q < 4; ++q) {
                    int r = rbase + lg*4 + q;
                    int j = jb*16 + lr;
                    Ss[r * LV + j] = (j <= r) ? f2bf(sacc[q]) : (unsigned short)0;
                }
            } else {
#pragma unroll
                for (int q = 0; q < 4; ++q) {
                    int r = rbase + lg*4 + q;
                    Ss[r * LV + jb*16 + lr] = 0;
                }
            }
        }
    }
    // no barrier needed: each wave reads only its own S rows below

    f32x4 oacc[2][5] = {};
#pragma unroll
    for (int m = 0; m < 2; ++m) {
        int rbase = w * 32 + m * 16;
        // inter-chunk: Q @ KV_state (K-dim 64)
#pragma unroll
        for (int ks = 0; ks < 2; ++ks) {
            bf16x8 a = *(const bf16x8*)&Qs[(rbase + lr) * LQ + ks*32 + lg*8];
#pragma unroll
            for (int n = 0; n < 5; ++n) {
                bf16x8 b = *(const bf16x8*)&KVt[(n*16 + lr) * LKV + ks*32 + lg*8];
                oacc[m][n] = __builtin_amdgcn_mfma_f32_16x16x32_bf16(a, b, oacc[m][n], 0, 0, 0);
            }
        }
        // intra-chunk: S @ V  (only k-blocks <= w are nonzero)
        for (int ks = 0; ks <= w; ++ks) {
            bf16x8 a = *(const bf16x8*)&Ss[(rbase + lr) * LV + ks*32 + lg*8];
#pragma unroll
            for (int n = 0; n < 5; ++n) {
                bf16x8 b = *(const bf16x8*)&Vt[(n*16 + lr) * LV + ks*32 + lg*8];
                oacc[m][n] = __builtin_amdgcn_mfma_f32_16x16x32_bf16(a, b, oacc[m][n], 0, 0, 0);
            }
        }
    }

    // den broadcast (col 64 lives in lanes with lr==0) + normalize + store
    int b_idx = bh >> 4, h_idx = bh & 15;
#pragma unroll
    for (int m = 0; m < 2; ++m) {
        int rbase = w * 32 + m * 16;
        float den[4];
#pragma unroll
        for (int q = 0; q < 4; ++q)
            den[q] = __shfl(oacc[m][4][q], lane & 48, 64) + EPS_DEN;
#pragma unroll
        for (int n = 0; n < 4; ++n) {
#pragma unroll
            for (int q = 0; q < 4; ++q) {
                int r = rbase + lg*4 + q;
                int lpos = c * CHK + r;
                int col = n*16 + lr;
                size_t dst = ((size_t)b_idx * L_ + lpos) * D_ + h_idx * 64 + col;
                attn[dst] = f2bf(oacc[m][n][q] / den[q]);
            }
        }
    }
}

// ---------------- launcher ----------------

extern "C" void kernel_launch(void* const* d_in, const int* in_sizes, int n_in,
                              void* d_out, int out_size, void* d_ws, size_t ws_size,
                              hipStream_t stream)
{
    const float* x    = (const float*)d_in[0];
    const float* Wqkv = (const float*)d_in[1];
    const float* bqkv = (const float*)d_in[2];
    const float* Wout = (const float*)d_in[3];
    const float* bout = (const float*)d_in[4];
    float* out = (float*)d_out;

    char* ws = (char*)d_ws;
    size_t off = 0;
    auto alloc = [&](size_t bytes) { void* p = ws + off; off += (bytes + 255) & ~(size_t)255; return p; };
    unsigned short* xb  = (unsigned short*)alloc((size_t)M_ * D_ * 2);
    unsigned short* WqT = (unsigned short*)alloc((size_t)N1_ * D_ * 2);
    unsigned short* WoT = (unsigned short*)alloc((size_t)D_ * D_ * 2);
    unsigned short* qfb = (unsigned short*)alloc((size_t)M_ * D_ * 2);
    unsigned short* kfb = (unsigned short*)alloc((size_t)M_ * D_ * 2);
    unsigned short* vfb = (unsigned short*)alloc((size_t)M_ * D_ * 2);
    float* kvw = (float*)alloc((size_t)BH * NC * E_ * E_ * 4);
    float* ksw = (float*)alloc((size_t)BH * NC * E_ * 4);
    unsigned short* attn = xb;   // alias: x_bf16 is dead after gemm1

    cvt_x<<<(M_ * D_ / 4) / 256, 256, 0, stream>>>(x, xb);
    transp_w<<<dim3(N1_ / 32, D_ / 32), 256, 0, stream>>>(Wqkv, WqT, D_, N1_);
    transp_w<<<dim3(D_ / 32, D_ / 32), 256, 0, stream>>>(Wout, WoT, D_, D_);

    gemm_bt<0><<<dim3(N1_ / 128, M_ / 128), 256, 0, stream>>>(
        xb, WqT, bqkv, D_, N1_, nullptr, qfb, kfb, vfb);

    chunk_kv<<<BH * NC, 256, 0, stream>>>(kfb, vfb, kvw, ksw);
    prefix_kv<<<BH, 256, 0, stream>>>(kvw, ksw);
    attn_out<<<BH * NC, 256, 0, stream>>>(qfb, kfb, vfb, kvw, ksw, attn);

    gemm_bt<1><<<dim3(D_ / 128, M_ / 128), 256, 0, stream>>>(
        attn, WoT, bout, D_, D_, out, nullptr, nullptr, nullptr);
}

// Round 3
// 347.636 us; speedup vs baseline: 1.0292x; 1.0292x over previous
//
#include <hip/hip_runtime.h>
#include <hip/hip_bf16.h>
#include <stdint.h>

#define B_ 4
#define L_ 4096
#define D_ 1024
#define H_ 16
#define E_ 64
#define M_ (B_*L_)       // 16384 rows
#define N1_ (3*D_)       // 3072
#define CHK 128
#define NC (L_/CHK)      // 32
#define BH (B_*H_)       // 64

#define EPS_FEAT 1.0001f
#define EPS_DEN 1e-6f

typedef __attribute__((ext_vector_type(4))) float f32x4;
typedef __attribute__((ext_vector_type(8))) short bf16x8;

__device__ __forceinline__ unsigned short f2bf(float x) {
    union { float f; unsigned int u; } v; v.f = x;
    unsigned int r = v.u + 0x7FFFu + ((v.u >> 16) & 1u);
    return (unsigned short)(r >> 16);
}

// async global->LDS, 16B per lane. LDS dest = wave-uniform base + lane*16.
__device__ __forceinline__ void gload_lds16(const unsigned short* g, unsigned short* l) {
    __builtin_amdgcn_global_load_lds(
        (const __attribute__((address_space(1))) unsigned int*)(const void*)g,
        (__attribute__((address_space(3))) unsigned int*)(void*)l,
        16, 0, 0);
}

// ---------------- prep kernels ----------------

__global__ __launch_bounds__(256) void cvt_x(const float* __restrict__ x,
                                             unsigned short* __restrict__ xb) {
    int i4 = blockIdx.x * 256 + threadIdx.x;      // float4 index
    float4 v = ((const float4*)x)[i4];
    unsigned int lo = (unsigned int)f2bf(v.x) | ((unsigned int)f2bf(v.y) << 16);
    unsigned int hi = (unsigned int)f2bf(v.z) | ((unsigned int)f2bf(v.w) << 16);
    ((uint2*)xb)[i4] = make_uint2(lo, hi);
}

// W (K,N) f32 -> WT (N,K) bf16
__global__ __launch_bounds__(256) void transp_w(const float* __restrict__ W,
                                                unsigned short* __restrict__ WT,
                                                int K, int N) {
    __shared__ float tile[32][33];
    int kb = blockIdx.y * 32, nb = blockIdx.x * 32;
    int tx = threadIdx.x & 31, ty = threadIdx.x >> 5;   // ty 0..7
#pragma unroll
    for (int j = 0; j < 4; ++j)
        tile[ty + 8*j][tx] = W[(size_t)(kb + ty + 8*j) * N + nb + tx];
    __syncthreads();
#pragma unroll
    for (int j = 0; j < 4; ++j) {
        int nl = ty + 8*j;
        WT[(size_t)(nb + nl) * K + kb + tx] = f2bf(tile[tx][nl]);
    }
}

// ---------------- GEMM (A bf16 MxK, BT bf16 NxK) ----------------
// MODE 0: qkv epilogue (feature map, split into q/k/v buffers (B,H,L,E))
// MODE 1: plain f32 output + bias
// Staging via global_load_lds width=16 into LINEAR [128][32] LDS (m97 structure).

template<int MODE>
__global__ __launch_bounds__(256) void gemm_bt(
    const unsigned short* __restrict__ A,
    const unsigned short* __restrict__ BT,
    const float* __restrict__ bias,
    int Kdim, int Ndim,
    float* __restrict__ outF,
    unsigned short* __restrict__ qf,
    unsigned short* __restrict__ kf,
    unsigned short* __restrict__ vf)
{
    __shared__ unsigned short As[128 * 32];   // linear, stride 32 elems (64B rows)
    __shared__ unsigned short Bs[128 * 32];

    int t = threadIdx.x, lane = t & 63, w = t >> 6;
    int wm = w >> 1, wn = w & 1;
    int m0 = blockIdx.y * 128, n0 = blockIdx.x * 128;
    int lr = lane & 15, lg = lane >> 4;

    // per-thread staging coords: thread s (+256) covers row s>>2, col (s&3)*8
    int r0 = t >> 2, c0 = (t & 3) << 3;

    f32x4 acc[4][4] = {};

    for (int kt = 0; kt < Kdim; kt += 32) {
#pragma unroll
        for (int it = 0; it < 2; ++it) {
            int s = it * 256 + t;
            int row = r0 + it * 64;
            gload_lds16(A  + (size_t)(m0 + row) * Kdim + kt + c0, &As[s * 8]);
            gload_lds16(BT + (size_t)(n0 + row) * Kdim + kt + c0, &Bs[s * 8]);
        }
        __syncthreads();
        bf16x8 af[4], bfr[4];
#pragma unroll
        for (int m = 0; m < 4; ++m)
            af[m] = *(const bf16x8*)&As[(wm*64 + m*16 + lr) * 32 + lg*8];
#pragma unroll
        for (int n = 0; n < 4; ++n)
            bfr[n] = *(const bf16x8*)&Bs[(wn*64 + n*16 + lr) * 32 + lg*8];
#pragma unroll
        for (int m = 0; m < 4; ++m)
#pragma unroll
            for (int n = 0; n < 4; ++n)
                acc[m][n] = __builtin_amdgcn_mfma_f32_16x16x32_bf16(af[m], bfr[n], acc[m][n], 0, 0, 0);
        __syncthreads();
    }

    // epilogue. D element: row = m0+wm*64+m*16+lg*4+q, col = n0+wn*64+n*16+lr
#pragma unroll
    for (int n = 0; n < 4; ++n) {
        int c = n0 + wn*64 + n*16 + lr;
        float bv = bias[c];
#pragma unroll
        for (int m = 0; m < 4; ++m) {
#pragma unroll
            for (int q = 0; q < 4; ++q) {
                int r = m0 + wm*64 + m*16 + lg*4 + q;
                float val = acc[m][n][q] + bv;
                if (MODE == 0) {
                    int b = r >> 12, l = r & 4095;
                    int h = (c & 1023) >> 6, e = c & 63;
                    size_t dst = (((size_t)(b * H_ + h)) * L_ + l) * E_ + e;
                    if (c < D_) {
                        float xq = val * 0.125f;                       // E^-0.5
                        float fq = xq > 0.f ? xq : __expf(xq) - 1.f;   // elu
                        qf[dst] = f2bf(fq + EPS_FEAT);
                    } else if (c < 2 * D_) {
                        float fk = val > 0.f ? val : __expf(val) - 1.f;
                        kf[dst] = f2bf(fk + EPS_FEAT);
                    } else {
                        vf[dst] = f2bf(val);
                    }
                } else {
                    outF[(size_t)r * Ndim + c] = val;
                }
            }
        }
    }
}

// ---------------- chunk KV: KV_c[e][f] = sum_l K[l][e] V[l][f], ksum_c[e] ----------------

__global__ __launch_bounds__(256) void chunk_kv(
    const unsigned short* __restrict__ kf, const unsigned short* __restrict__ vf,
    float* __restrict__ kvout, float* __restrict__ ksout)
{
    constexpr int LDK = 136;                 // 128 + 8 pad
    __shared__ unsigned short Kt[64 * LDK];  // K^T : [e][l]
    __shared__ unsigned short Vt[80 * LDK];  // V^T : [f][l], row 64 = ones (ksum trick)

    int t = threadIdx.x, lane = t & 63, w = t >> 6;
    int bid = blockIdx.x;                    // bh*NC + c
    const unsigned short* kp = kf + (size_t)bid * CHK * E_;
    const unsigned short* vp = vf + (size_t)bid * CHK * E_;

#pragma unroll
    for (int it = 0; it < 4; ++it) {
        int s = it * 256 + t;                // 0..1023  (16B granules of 128x64)
        int rl = s >> 3, e0 = (s & 7) << 3;
        uint4 kv8 = *(const uint4*)(kp + s * 8);
        uint4 vv8 = *(const uint4*)(vp + s * 8);
        unsigned int kw[4] = {kv8.x, kv8.y, kv8.z, kv8.w};
        unsigned int vw[4] = {vv8.x, vv8.y, vv8.z, vv8.w};
#pragma unroll
        for (int jw = 0; jw < 4; ++jw) {
            Kt[(e0 + 2*jw    ) * LDK + rl] = (unsigned short)(kw[jw] & 0xFFFF);
            Kt[(e0 + 2*jw + 1) * LDK + rl] = (unsigned short)(kw[jw] >> 16);
            Vt[(e0 + 2*jw    ) * LDK + rl] = (unsigned short)(vw[jw] & 0xFFFF);
            Vt[(e0 + 2*jw + 1) * LDK + rl] = (unsigned short)(vw[jw] >> 16);
        }
    }
    if (t < 128) Vt[64 * LDK + t] = 0x3F80;  // bf16 1.0
    for (int i = t; i < 15 * LDK; i += 256) Vt[65 * LDK + i] = 0;
    __syncthreads();

    int lr = lane & 15, lg = lane >> 4;
    f32x4 acc[5] = {};
#pragma unroll
    for (int ks = 0; ks < 4; ++ks) {
        bf16x8 a = *(const bf16x8*)&Kt[(w*16 + lr) * LDK + ks*32 + lg*8];
#pragma unroll
        for (int n = 0; n < 5; ++n) {
            bf16x8 b = *(const bf16x8*)&Vt[(n*16 + lr) * LDK + ks*32 + lg*8];
            acc[n] = __builtin_amdgcn_mfma_f32_16x16x32_bf16(a, b, acc[n], 0, 0, 0);
        }
    }
    float* kvo = kvout + (size_t)bid * E_ * E_;
#pragma unroll
    for (int n = 0; n < 4; ++n)
#pragma unroll
        for (int q = 0; q < 4; ++q) {
            int e = w*16 + lg*4 + q, f = n*16 + lr;
            kvo[e * 64 + f] = acc[n][q];
        }
    if (lr == 0) {
#pragma unroll
        for (int q = 0; q < 4; ++q) {
            int e = w*16 + lg*4 + q;
            ksout[(size_t)bid * 64 + e] = acc[4][q];
        }
    }
}

// ---------------- exclusive prefix over chunks (per bh) ----------------

__global__ __launch_bounds__(256) void prefix_kv(float* __restrict__ kv, float* __restrict__ ks) {
    int bh = blockIdx.x, t = threadIdx.x;
    float st[16];
#pragma unroll
    for (int j = 0; j < 16; ++j) st[j] = 0.f;
    for (int c = 0; c < NC; ++c) {
        float* p = kv + ((size_t)bh * NC + c) * 4096;
#pragma unroll
        for (int j = 0; j < 16; ++j) {
            float tmp = p[j * 256 + t];
            p[j * 256 + t] = st[j];
            st[j] += tmp;
        }
    }
    if (t < 64) {
        float s0 = 0.f;
        for (int c = 0; c < NC; ++c) {
            float* p = ks + ((size_t)bh * NC + c) * 64;
            float tmp = p[t]; p[t] = s0; s0 += tmp;
        }
    }
}

// ---------------- attention output per (bh, chunk) ----------------

__global__ __launch_bounds__(256) void attn_out(
    const unsigned short* __restrict__ qf, const unsigned short* __restrict__ kf,
    const unsigned short* __restrict__ vf, const float* __restrict__ kvst,
    const float* __restrict__ ksst, unsigned short* __restrict__ attn)
{
    constexpr int LQ = 72;    // Q/K stride (64+8)
    constexpr int LV = 136;   // Vt & S stride (128+8)
    constexpr int LKV = 72;   // KVt stride (64+8)
    __shared__ unsigned short Qs[128 * LQ];
    __shared__ unsigned short Ks[128 * LQ];
    __shared__ unsigned short Vt[80 * LV];    // row 64 = ones
    __shared__ unsigned short KVt[80 * LKV];  // row 64 = ksum
    __shared__ unsigned short Ss[128 * LV];

    int t = threadIdx.x, lane = t & 63, w = t >> 6;
    int bid = blockIdx.x;
    int bh = bid >> 5, c = bid & 31;
    const unsigned short* qp = qf + (size_t)bid * CHK * E_;
    const unsigned short* kp = kf + (size_t)bid * CHK * E_;
    const unsigned short* vp = vf + (size_t)bid * CHK * E_;

#pragma unroll
    for (int it = 0; it < 4; ++it) {
        int s = it * 256 + t;
        int r = s >> 3, e0 = (s & 7) << 3;
        uint4 qv = *(const uint4*)(qp + s * 8);
        uint4 kv = *(const uint4*)(kp + s * 8);
        uint4 vv = *(const uint4*)(vp + s * 8);
        *(uint4*)&Qs[r * LQ + e0] = qv;
        *(uint4*)&Ks[r * LQ + e0] = kv;
        unsigned int vw[4] = {vv.x, vv.y, vv.z, vv.w};
#pragma unroll
        for (int jw = 0; jw < 4; ++jw) {
            Vt[(e0 + 2*jw    ) * LV + r] = (unsigned short)(vw[jw] & 0xFFFF);
            Vt[(e0 + 2*jw + 1) * LV + r] = (unsigned short)(vw[jw] >> 16);
        }
    }
    const float* kvp = kvst + (size_t)bid * 4096;
#pragma unroll
    for (int it = 0; it < 16; ++it) {
        int idx = it * 256 + t;
        int e = idx >> 6, f = idx & 63;
        KVt[f * LKV + e] = f2bf(kvp[idx]);
    }
    if (t < 64)  KVt[64 * LKV + t] = f2bf(ksst[(size_t)bid * 64 + t]);
    if (t < 128) Vt[64 * LV + t] = 0x3F80;
    for (int i = t; i < 15 * LV;  i += 256) Vt[65 * LV  + i] = 0;
    for (int i = t; i < 15 * LKV; i += 256) KVt[65 * LKV + i] = 0;
    __syncthreads();

    int lr = lane & 15, lg = lane >> 4;

    // S-phase: wave w owns rows [w*32, w*32+32)
#pragma unroll
    for (int m = 0; m < 2; ++m) {
        int rbase = w * 32 + m * 16;
        bf16x8 aq0 = *(const bf16x8*)&Qs[(rbase + lr) * LQ + lg*8];
        bf16x8 aq1 = *(const bf16x8*)&Qs[(rbase + lr) * LQ + 32 + lg*8];
        int jmax = 2 * w + m;
        for (int jb = 0; jb < 8; ++jb) {
            if (jb <= jmax) {
                f32x4 sacc = {};
                bf16x8 b0 = *(const bf16x8*)&Ks[(jb*16 + lr) * LQ + lg*8];
                bf16x8 b1 = *(const bf16x8*)&Ks[(jb*16 + lr) * LQ + 32 + lg*8];
                sacc = __builtin_amdgcn_mfma_f32_16x16x32_bf16(aq0, b0, sacc, 0, 0, 0);
                sacc = __builtin_amdgcn_mfma_f32_16x16x32_bf16(aq1, b1, sacc, 0, 0, 0);
#pragma unroll
                for (int q = 0; q < 4; ++q) {
                    int r = rbase + lg*4 + q;
                    int j = jb*16 + lr;
                    Ss[r * LV + j] = (j <= r) ? f2bf(sacc[q]) : (unsigned short)0;
                }
            } else {
#pragma unroll
                for (int q = 0; q < 4; ++q) {
                    int r = rbase + lg*4 + q;
                    Ss[r * LV + jb*16 + lr] = 0;
                }
            }
        }
    }
    // no barrier needed: each wave reads only its own S rows below

    f32x4 oacc[2][5] = {};
#pragma unroll
    for (int m = 0; m < 2; ++m) {
        int rbase = w * 32 + m * 16;
        // inter-chunk: Q @ KV_state (K-dim 64)
#pragma unroll
        for (int ks = 0; ks < 2; ++ks) {
            bf16x8 a = *(const bf16x8*)&Qs[(rbase + lr) * LQ + ks*32 + lg*8];
#pragma unroll
            for (int n = 0; n < 5; ++n) {
                bf16x8 b = *(const bf16x8*)&KVt[(n*16 + lr) * LKV + ks*32 + lg*8];
                oacc[m][n] = __builtin_amdgcn_mfma_f32_16x16x32_bf16(a, b, oacc[m][n], 0, 0, 0);
            }
        }
        // intra-chunk: S @ V  (only k-blocks <= w are nonzero)
        for (int ks = 0; ks <= w; ++ks) {
            bf16x8 a = *(const bf16x8*)&Ss[(rbase + lr) * LV + ks*32 + lg*8];
#pragma unroll
            for (int n = 0; n < 5; ++n) {
                bf16x8 b = *(const bf16x8*)&Vt[(n*16 + lr) * LV + ks*32 + lg*8];
                oacc[m][n] = __builtin_amdgcn_mfma_f32_16x16x32_bf16(a, b, oacc[m][n], 0, 0, 0);
            }
        }
    }

    // den broadcast (col 64 lives in lanes with lr==0) + normalize + store
    int b_idx = bh >> 4, h_idx = bh & 15;
#pragma unroll
    for (int m = 0; m < 2; ++m) {
        int rbase = w * 32 + m * 16;
        float den[4];
#pragma unroll
        for (int q = 0; q < 4; ++q)
            den[q] = __shfl(oacc[m][4][q], lane & 48, 64) + EPS_DEN;
#pragma unroll
        for (int n = 0; n < 4; ++n) {
#pragma unroll
            for (int q = 0; q < 4; ++q) {
                int r = rbase + lg*4 + q;
                int lpos = c * CHK + r;
                int col = n*16 + lr;
                size_t dst = ((size_t)b_idx * L_ + lpos) * D_ + h_idx * 64 + col;
                attn[dst] = f2bf(oacc[m][n][q] / den[q]);
            }
        }
    }
}

// ---------------- launcher ----------------

extern "C" void kernel_launch(void* const* d_in, const int* in_sizes, int n_in,
                              void* d_out, int out_size, void* d_ws, size_t ws_size,
                              hipStream_t stream)
{
    const float* x    = (const float*)d_in[0];
    const float* Wqkv = (const float*)d_in[1];
    const float* bqkv = (const float*)d_in[2];
    const float* Wout = (const float*)d_in[3];
    const float* bout = (const float*)d_in[4];
    float* out = (float*)d_out;

    char* ws = (char*)d_ws;
    size_t off = 0;
    auto alloc = [&](size_t bytes) { void* p = ws + off; off += (bytes + 255) & ~(size_t)255; return p; };
    unsigned short* xb  = (unsigned short*)alloc((size_t)M_ * D_ * 2);
    unsigned short* WqT = (unsigned short*)alloc((size_t)N1_ * D_ * 2);
    unsigned short* WoT = (unsigned short*)alloc((size_t)D_ * D_ * 2);
    unsigned short* qfb = (unsigned short*)alloc((size_t)M_ * D_ * 2);
    unsigned short* kfb = (unsigned short*)alloc((size_t)M_ * D_ * 2);
    unsigned short* vfb = (unsigned short*)alloc((size_t)M_ * D_ * 2);
    float* kvw = (float*)alloc((size_t)BH * NC * E_ * E_ * 4);
    float* ksw = (float*)alloc((size_t)BH * NC * E_ * 4);
    unsigned short* attn = xb;   // alias: x_bf16 is dead after gemm1

    cvt_x<<<(M_ * D_ / 4) / 256, 256, 0, stream>>>(x, xb);
    transp_w<<<dim3(N1_ / 32, D_ / 32), 256, 0, stream>>>(Wqkv, WqT, D_, N1_);
    transp_w<<<dim3(D_ / 32, D_ / 32), 256, 0, stream>>>(Wout, WoT, D_, D_);

    gemm_bt<0><<<dim3(N1_ / 128, M_ / 128), 256, 0, stream>>>(
        xb, WqT, bqkv, D_, N1_, nullptr, qfb, kfb, vfb);

    chunk_kv<<<BH * NC, 256, 0, stream>>>(kfb, vfb, kvw, ksw);
    prefix_kv<<<BH, 256, 0, stream>>>(kvw, ksw);
    attn_out<<<BH * NC, 256, 0, stream>>>(qfb, kfb, vfb, kvw, ksw, attn);

    gemm_bt<1><<<dim3(D_ / 128, M_ / 128), 256, 0, stream>>>(
        attn, WoT, bout, D_, D_, out, nullptr, nullptr, nullptr);
}

// Round 4
// 342.325 us; speedup vs baseline: 1.0452x; 1.0155x over previous
//
#include <hip/hip_runtime.h>
#include <hip/hip_bf16.h>
#include <stdint.h>

#define B_ 4
#define L_ 4096
#define D_ 1024
#define H_ 16
#define E_ 64
#define M_ (B_*L_)       // 16384 rows
#define N1_ (3*D_)       // 3072
#define CHK 128
#define NC (L_/CHK)      // 32
#define BH (B_*H_)       // 64

#define EPS_FEAT 1.0001f
#define EPS_DEN 1e-6f

typedef __attribute__((ext_vector_type(4))) float f32x4;
typedef __attribute__((ext_vector_type(8))) short bf16x8;

__device__ __forceinline__ unsigned short f2bf(float x) {
    union { float f; unsigned int u; } v; v.f = x;
    unsigned int r = v.u + 0x7FFFu + ((v.u >> 16) & 1u);
    return (unsigned short)(r >> 16);
}

// async global->LDS, 16B per lane. LDS dest = wave-uniform base + lane*16.
__device__ __forceinline__ void gload_lds16(const unsigned short* g, unsigned short* l) {
    __builtin_amdgcn_global_load_lds(
        (const __attribute__((address_space(1))) unsigned int*)(const void*)g,
        (__attribute__((address_space(3))) unsigned int*)(void*)l,
        16, 0, 0);
}

// ---------------- prep kernels ----------------

__global__ __launch_bounds__(256) void cvt_x(const float* __restrict__ x,
                                             unsigned short* __restrict__ xb) {
    int i4 = blockIdx.x * 256 + threadIdx.x;      // float4 index
    float4 v = ((const float4*)x)[i4];
    unsigned int lo = (unsigned int)f2bf(v.x) | ((unsigned int)f2bf(v.y) << 16);
    unsigned int hi = (unsigned int)f2bf(v.z) | ((unsigned int)f2bf(v.w) << 16);
    ((uint2*)xb)[i4] = make_uint2(lo, hi);
}

// W (K,N) f32 -> WT (N,K) bf16
__global__ __launch_bounds__(256) void transp_w(const float* __restrict__ W,
                                                unsigned short* __restrict__ WT,
                                                int K, int N) {
    __shared__ float tile[32][33];
    int kb = blockIdx.y * 32, nb = blockIdx.x * 32;
    int tx = threadIdx.x & 31, ty = threadIdx.x >> 5;   // ty 0..7
#pragma unroll
    for (int j = 0; j < 4; ++j)
        tile[ty + 8*j][tx] = W[(size_t)(kb + ty + 8*j) * N + nb + tx];
    __syncthreads();
#pragma unroll
    for (int j = 0; j < 4; ++j) {
        int nl = ty + 8*j;
        WT[(size_t)(nb + nl) * K + kb + tx] = f2bf(tile[tx][nl]);
    }
}

// ---------------- GEMM (A bf16 MxK, BT bf16 NxK) ----------------
// MODE 0: qkv epilogue (feature map, split into q/k/v buffers (B,H,L,E))
// MODE 1: plain f32 output + bias
// Staging via global_load_lds width=16 into LINEAR [128][32] LDS (m97 structure).
// Epilogue routed through LDS C-tile for coalesced stores (K=1024 -> epilogue matters).

template<int MODE, int KDIM, int NDIM>
__global__ __launch_bounds__(256) void gemm_bt(
    const unsigned short* __restrict__ A,
    const unsigned short* __restrict__ BT,
    const float* __restrict__ bias,
    float* __restrict__ outF,
    unsigned short* __restrict__ qf,
    unsigned short* __restrict__ kf,
    unsigned short* __restrict__ vf)
{
    // 34.8 KB shared: staging (16KB) then reused as C-tile in epilogue
    __shared__ __align__(16) unsigned short smem[17408];
    unsigned short* As = smem;           // [128][32] linear
    unsigned short* Bs = smem + 4096;    // [128][32] linear

    int t = threadIdx.x, lane = t & 63, w = t >> 6;
    int wm = w >> 1, wn = w & 1;
    int m0 = blockIdx.y * 128, n0 = blockIdx.x * 128;
    int lr = lane & 15, lg = lane >> 4;

    int r0 = t >> 2, c0 = (t & 3) << 3;

    f32x4 acc[4][4] = {};

    for (int kt = 0; kt < KDIM; kt += 32) {
#pragma unroll
        for (int it = 0; it < 2; ++it) {
            int s = it * 256 + t;
            int row = r0 + it * 64;
            gload_lds16(A  + (size_t)(m0 + row) * KDIM + kt + c0, &As[s * 8]);
            gload_lds16(BT + (size_t)(n0 + row) * KDIM + kt + c0, &Bs[s * 8]);
        }
        __syncthreads();
        bf16x8 af[4], bfr[4];
#pragma unroll
        for (int m = 0; m < 4; ++m)
            af[m] = *(const bf16x8*)&As[(wm*64 + m*16 + lr) * 32 + lg*8];
#pragma unroll
        for (int n = 0; n < 4; ++n)
            bfr[n] = *(const bf16x8*)&Bs[(wn*64 + n*16 + lr) * 32 + lg*8];
#pragma unroll
        for (int m = 0; m < 4; ++m)
#pragma unroll
            for (int n = 0; n < 4; ++n)
                acc[m][n] = __builtin_amdgcn_mfma_f32_16x16x32_bf16(af[m], bfr[n], acc[m][n], 0, 0, 0);
        __syncthreads();
    }

    if (MODE == 0) {
        // ---- qkv epilogue: LDS C-tile [128][136] bf16 ----
        unsigned short* cbf = smem;            // stride 136
        bool isQ = (n0 < D_), isK = (n0 >= D_ && n0 < 2*D_);
        float scale = isQ ? 0.125f : 1.0f;
#pragma unroll
        for (int n = 0; n < 4; ++n) {
            int cl = wn*64 + n*16 + lr;
            float bv = bias[n0 + cl];
#pragma unroll
            for (int m = 0; m < 4; ++m)
#pragma unroll
                for (int q = 0; q < 4; ++q) {
                    int rl = wm*64 + m*16 + lg*4 + q;
                    float val = (acc[m][n][q] + bv) * scale;
                    float fv;
                    if (isQ || isK)
                        fv = (val > 0.f ? val : __expf(val) - 1.f) + EPS_FEAT;
                    else
                        fv = val;
                    cbf[rl * 136 + cl] = f2bf(fv);
                }
        }
        __syncthreads();
        unsigned short* buf = isQ ? qf : (isK ? kf : vf);
        int b = m0 >> 12, l0 = m0 & 4095;
        int h0 = (n0 >> 6) & 15;
        int row = t >> 1, e0 = (t & 1) * 32;
#pragma unroll
        for (int hh = 0; hh < 2; ++hh) {
            unsigned short* dst = buf + (((size_t)(b * H_ + h0 + hh)) * L_ + l0) * E_;
#pragma unroll
            for (int j = 0; j < 4; ++j) {
                uint4 v = *(const uint4*)&cbf[row * 136 + hh * 64 + e0 + j * 8];
                *(uint4*)&dst[row * 64 + e0 + j * 8] = v;
            }
        }
    } else {
        // ---- f32 epilogue: two row-half passes through LDS [64][132] f32 ----
        float* cfl = (float*)smem;             // stride 132
#pragma unroll
        for (int p = 0; p < 2; ++p) {
            if (wm == p) {
#pragma unroll
                for (int n = 0; n < 4; ++n) {
                    int cl = wn*64 + n*16 + lr;
                    float bv = bias[n0 + cl];
#pragma unroll
                    for (int m = 0; m < 4; ++m)
#pragma unroll
                        for (int q = 0; q < 4; ++q) {
                            int r2 = m*16 + lg*4 + q;
                            cfl[r2 * 132 + cl] = acc[m][n][q] + bv;
                        }
                }
            }
            __syncthreads();
            int row = t >> 2, c2 = (t & 3) * 32;
#pragma unroll
            for (int j = 0; j < 8; ++j) {
                float4 v = *(const float4*)&cfl[row * 132 + c2 + j * 4];
                *(float4*)&outF[(size_t)(m0 + p*64 + row) * NDIM + n0 + c2 + j * 4] = v;
            }
            __syncthreads();
        }
    }
}

// ---------------- chunk KV: KV_c[e][f] = sum_l K[l][e] V[l][f], ksum_c[e] ----------------

__global__ __launch_bounds__(256) void chunk_kv(
    const unsigned short* __restrict__ kf, const unsigned short* __restrict__ vf,
    float* __restrict__ kvout, float* __restrict__ ksout)
{
    constexpr int LDK = 136;                 // 128 + 8 pad
    __shared__ unsigned short Kt[64 * LDK];  // K^T : [e][l]
    __shared__ unsigned short Vt[80 * LDK];  // V^T : [f][l], row 64 = ones (ksum trick)

    int t = threadIdx.x, lane = t & 63, w = t >> 6;
    int bid = blockIdx.x;                    // bh*NC + c
    const unsigned short* kp = kf + (size_t)bid * CHK * E_;
    const unsigned short* vp = vf + (size_t)bid * CHK * E_;

#pragma unroll
    for (int it = 0; it < 4; ++it) {
        int s = it * 256 + t;                // 0..1023  (16B granules of 128x64)
        int rl = s >> 3, e0 = (s & 7) << 3;
        uint4 kv8 = *(const uint4*)(kp + s * 8);
        uint4 vv8 = *(const uint4*)(vp + s * 8);
        unsigned int kw[4] = {kv8.x, kv8.y, kv8.z, kv8.w};
        unsigned int vw[4] = {vv8.x, vv8.y, vv8.z, vv8.w};
#pragma unroll
        for (int jw = 0; jw < 4; ++jw) {
            Kt[(e0 + 2*jw    ) * LDK + rl] = (unsigned short)(kw[jw] & 0xFFFF);
            Kt[(e0 + 2*jw + 1) * LDK + rl] = (unsigned short)(kw[jw] >> 16);
            Vt[(e0 + 2*jw    ) * LDK + rl] = (unsigned short)(vw[jw] & 0xFFFF);
            Vt[(e0 + 2*jw + 1) * LDK + rl] = (unsigned short)(vw[jw] >> 16);
        }
    }
    if (t < 128) Vt[64 * LDK + t] = 0x3F80;  // bf16 1.0
    for (int i = t; i < 15 * LDK; i += 256) Vt[65 * LDK + i] = 0;
    __syncthreads();

    int lr = lane & 15, lg = lane >> 4;
    f32x4 acc[5] = {};
#pragma unroll
    for (int ks = 0; ks < 4; ++ks) {
        bf16x8 a = *(const bf16x8*)&Kt[(w*16 + lr) * LDK + ks*32 + lg*8];
#pragma unroll
        for (int n = 0; n < 5; ++n) {
            bf16x8 b = *(const bf16x8*)&Vt[(n*16 + lr) * LDK + ks*32 + lg*8];
            acc[n] = __builtin_amdgcn_mfma_f32_16x16x32_bf16(a, b, acc[n], 0, 0, 0);
        }
    }
    float* kvo = kvout + (size_t)bid * E_ * E_;
#pragma unroll
    for (int n = 0; n < 4; ++n)
#pragma unroll
        for (int q = 0; q < 4; ++q) {
            int e = w*16 + lg*4 + q, f = n*16 + lr;
            kvo[e * 64 + f] = acc[n][q];
        }
    if (lr == 0) {
#pragma unroll
        for (int q = 0; q < 4; ++q) {
            int e = w*16 + lg*4 + q;
            ksout[(size_t)bid * 64 + e] = acc[4][q];
        }
    }
}

// ---------------- exclusive prefix over chunks (per bh) ----------------

__global__ __launch_bounds__(256) void prefix_kv(float* __restrict__ kv, float* __restrict__ ks) {
    int bh = blockIdx.y, part = blockIdx.x, t = threadIdx.x;
    float st[4];
#pragma unroll
    for (int j = 0; j < 4; ++j) st[j] = 0.f;
    for (int c = 0; c < NC; ++c) {
        float* p = kv + ((size_t)bh * NC + c) * 4096 + part * 1024;
#pragma unroll
        for (int j = 0; j < 4; ++j) {
            float tmp = p[j * 256 + t];
            p[j * 256 + t] = st[j];
            st[j] += tmp;
        }
    }
    if (part == 0 && t < 64) {
        float s0 = 0.f;
        for (int c = 0; c < NC; ++c) {
            float* p = ks + ((size_t)bh * NC + c) * 64;
            float tmp = p[t]; p[t] = s0; s0 += tmp;
        }
    }
}

// ---------------- attention output per (bh, chunk) ----------------

__global__ __launch_bounds__(256) void attn_out(
    const unsigned short* __restrict__ qf, const unsigned short* __restrict__ kf,
    const unsigned short* __restrict__ vf, const float* __restrict__ kvst,
    const float* __restrict__ ksst, unsigned short* __restrict__ attn)
{
    constexpr int LQ = 72;    // Q/K stride (64+8)
    constexpr int LV = 136;   // Vt & S stride (128+8)
    constexpr int LKV = 72;   // KVt stride (64+8)
    __shared__ unsigned short Qs[128 * LQ];
    __shared__ unsigned short Ks[128 * LQ];
    __shared__ unsigned short Vt[80 * LV];    // row 64 = ones
    __shared__ unsigned short KVt[80 * LKV];  // row 64 = ksum
    __shared__ unsigned short Ss[128 * LV];

    int t = threadIdx.x, lane = t & 63, w = t >> 6;
    int bid = blockIdx.x;
    int bh = bid >> 5, c = bid & 31;
    const unsigned short* qp = qf + (size_t)bid * CHK * E_;
    const unsigned short* kp = kf + (size_t)bid * CHK * E_;
    const unsigned short* vp = vf + (size_t)bid * CHK * E_;

#pragma unroll
    for (int it = 0; it < 4; ++it) {
        int s = it * 256 + t;
        int r = s >> 3, e0 = (s & 7) << 3;
        uint4 qv = *(const uint4*)(qp + s * 8);
        uint4 kv = *(const uint4*)(kp + s * 8);
        uint4 vv = *(const uint4*)(vp + s * 8);
        *(uint4*)&Qs[r * LQ + e0] = qv;
        *(uint4*)&Ks[r * LQ + e0] = kv;
        unsigned int vw[4] = {vv.x, vv.y, vv.z, vv.w};
#pragma unroll
        for (int jw = 0; jw < 4; ++jw) {
            Vt[(e0 + 2*jw    ) * LV + r] = (unsigned short)(vw[jw] & 0xFFFF);
            Vt[(e0 + 2*jw + 1) * LV + r] = (unsigned short)(vw[jw] >> 16);
        }
    }
    const float* kvp = kvst + (size_t)bid * 4096;
#pragma unroll
    for (int it = 0; it < 16; ++it) {
        int idx = it * 256 + t;
        int e = idx >> 6, f = idx & 63;
        KVt[f * LKV + e] = f2bf(kvp[idx]);
    }
    if (t < 64)  KVt[64 * LKV + t] = f2bf(ksst[(size_t)bid * 64 + t]);
    if (t < 128) Vt[64 * LV + t] = 0x3F80;
    for (int i = t; i < 15 * LV;  i += 256) Vt[65 * LV  + i] = 0;
    for (int i = t; i < 15 * LKV; i += 256) KVt[65 * LKV + i] = 0;
    __syncthreads();

    int lr = lane & 15, lg = lane >> 4;

    // S-phase: wave w owns rows [w*32, w*32+32)
#pragma unroll
    for (int m = 0; m < 2; ++m) {
        int rbase = w * 32 + m * 16;
        bf16x8 aq0 = *(const bf16x8*)&Qs[(rbase + lr) * LQ + lg*8];
        bf16x8 aq1 = *(const bf16x8*)&Qs[(rbase + lr) * LQ + 32 + lg*8];
        int jmax = 2 * w + m;
        for (int jb = 0; jb < 8; ++jb) {
            if (jb <= jmax) {
                f32x4 sacc = {};
                bf16x8 b0 = *(const bf16x8*)&Ks[(jb*16 + lr) * LQ + lg*8];
                bf16x8 b1 = *(const bf16x8*)&Ks[(jb*16 + lr) * LQ + 32 + lg*8];
                sacc = __builtin_amdgcn_mfma_f32_16x16x32_bf16(aq0, b0, sacc, 0, 0, 0);
                sacc = __builtin_amdgcn_mfma_f32_16x16x32_bf16(aq1, b1, sacc, 0, 0, 0);
#pragma unroll
                for (int q = 0; q < 4; ++q) {
                    int r = rbase + lg*4 + q;
                    int j = jb*16 + lr;
                    Ss[r * LV + j] = (j <= r) ? f2bf(sacc[q]) : (unsigned short)0;
                }
            } else {
#pragma unroll
                for (int q = 0; q < 4; ++q) {
                    int r = rbase + lg*4 + q;
                    Ss[r * LV + jb*16 + lr] = 0;
                }
            }
        }
    }
    // no barrier needed: each wave reads only its own S rows below

    f32x4 oacc[2][5] = {};
#pragma unroll
    for (int m = 0; m < 2; ++m) {
        int rbase = w * 32 + m * 16;
        // inter-chunk: Q @ KV_state (K-dim 64)
#pragma unroll
        for (int ks = 0; ks < 2; ++ks) {
            bf16x8 a = *(const bf16x8*)&Qs[(rbase + lr) * LQ + ks*32 + lg*8];
#pragma unroll
            for (int n = 0; n < 5; ++n) {
                bf16x8 b = *(const bf16x8*)&KVt[(n*16 + lr) * LKV + ks*32 + lg*8];
                oacc[m][n] = __builtin_amdgcn_mfma_f32_16x16x32_bf16(a, b, oacc[m][n], 0, 0, 0);
            }
        }
        // intra-chunk: S @ V  (only k-blocks <= w are nonzero)
        for (int ks = 0; ks <= w; ++ks) {
            bf16x8 a = *(const bf16x8*)&Ss[(rbase + lr) * LV + ks*32 + lg*8];
#pragma unroll
            for (int n = 0; n < 5; ++n) {
                bf16x8 b = *(const bf16x8*)&Vt[(n*16 + lr) * LV + ks*32 + lg*8];
                oacc[m][n] = __builtin_amdgcn_mfma_f32_16x16x32_bf16(a, b, oacc[m][n], 0, 0, 0);
            }
        }
    }

    // den broadcast (col 64 lives in lanes with lr==0) + normalize + store
    int b_idx = bh >> 4, h_idx = bh & 15;
#pragma unroll
    for (int m = 0; m < 2; ++m) {
        int rbase = w * 32 + m * 16;
        float den[4];
#pragma unroll
        for (int q = 0; q < 4; ++q)
            den[q] = __shfl(oacc[m][4][q], lane & 48, 64) + EPS_DEN;
#pragma unroll
        for (int n = 0; n < 4; ++n) {
#pragma unroll
            for (int q = 0; q < 4; ++q) {
                int r = rbase + lg*4 + q;
                int lpos = c * CHK + r;
                int col = n*16 + lr;
                size_t dst = ((size_t)b_idx * L_ + lpos) * D_ + h_idx * 64 + col;
                attn[dst] = f2bf(oacc[m][n][q] / den[q]);
            }
        }
    }
}

// ---------------- launcher ----------------

extern "C" void kernel_launch(void* const* d_in, const int* in_sizes, int n_in,
                              void* d_out, int out_size, void* d_ws, size_t ws_size,
                              hipStream_t stream)
{
    const float* x    = (const float*)d_in[0];
    const float* Wqkv = (const float*)d_in[1];
    const float* bqkv = (const float*)d_in[2];
    const float* Wout = (const float*)d_in[3];
    const float* bout = (const float*)d_in[4];
    float* out = (float*)d_out;

    char* ws = (char*)d_ws;
    size_t off = 0;
    auto alloc = [&](size_t bytes) { void* p = ws + off; off += (bytes + 255) & ~(size_t)255; return p; };
    unsigned short* xb  = (unsigned short*)alloc((size_t)M_ * D_ * 2);
    unsigned short* WqT = (unsigned short*)alloc((size_t)N1_ * D_ * 2);
    unsigned short* WoT = (unsigned short*)alloc((size_t)D_ * D_ * 2);
    unsigned short* qfb = (unsigned short*)alloc((size_t)M_ * D_ * 2);
    unsigned short* kfb = (unsigned short*)alloc((size_t)M_ * D_ * 2);
    unsigned short* vfb = (unsigned short*)alloc((size_t)M_ * D_ * 2);
    float* kvw = (float*)alloc((size_t)BH * NC * E_ * E_ * 4);
    float* ksw = (float*)alloc((size_t)BH * NC * E_ * 4);
    unsigned short* attn = xb;   // alias: x_bf16 is dead after gemm1

    cvt_x<<<(M_ * D_ / 4) / 256, 256, 0, stream>>>(x, xb);
    transp_w<<<dim3(N1_ / 32, D_ / 32), 256, 0, stream>>>(Wqkv, WqT, D_, N1_);
    transp_w<<<dim3(D_ / 32, D_ / 32), 256, 0, stream>>>(Wout, WoT, D_, D_);

    gemm_bt<0, D_, N1_><<<dim3(N1_ / 128, M_ / 128), 256, 0, stream>>>(
        xb, WqT, bqkv, nullptr, qfb, kfb, vfb);

    chunk_kv<<<BH * NC, 256, 0, stream>>>(kfb, vfb, kvw, ksw);
    prefix_kv<<<dim3(4, BH), 256, 0, stream>>>(kvw, ksw);
    attn_out<<<BH * NC, 256, 0, stream>>>(qfb, kfb, vfb, kvw, ksw, attn);

    gemm_bt<1, D_, D_><<<dim3(D_ / 128, M_ / 128), 256, 0, stream>>>(
        attn, WoT, bout, out, nullptr, nullptr, nullptr);
}

// Round 5
// 287.227 us; speedup vs baseline: 1.2456x; 1.1918x over previous
//
#include <hip/hip_runtime.h>
#include <hip/hip_bf16.h>
#include <stdint.h>

#define B_ 4
#define L_ 4096
#define D_ 1024
#define H_ 16
#define E_ 64
#define M_ (B_*L_)       // 16384 rows
#define N1_ (3*D_)       // 3072
#define CHK 128
#define NC (L_/CHK)      // 32
#define BH (B_*H_)       // 64

#define EPS_FEAT 1.0001f
#define EPS_DEN 1e-6f

typedef __attribute__((ext_vector_type(4))) float f32x4;
typedef __attribute__((ext_vector_type(8))) short bf16x8;

__device__ __forceinline__ unsigned short f2bf(float x) {
    union { float f; unsigned int u; } v; v.f = x;
    unsigned int r = v.u + 0x7FFFu + ((v.u >> 16) & 1u);
    return (unsigned short)(r >> 16);
}

// async global->LDS, 16B per lane. LDS dest = wave-uniform base + lane*16.
__device__ __forceinline__ void gload_lds16(const unsigned short* g, unsigned short* l) {
    __builtin_amdgcn_global_load_lds(
        (const __attribute__((address_space(1))) unsigned int*)(const void*)g,
        (__attribute__((address_space(3))) unsigned int*)(void*)l,
        16, 0, 0);
}

// ---------------- prep kernels ----------------

__global__ __launch_bounds__(256) void cvt_x(const float* __restrict__ x,
                                             unsigned short* __restrict__ xb) {
    int i4 = blockIdx.x * 256 + threadIdx.x;      // float4 index
    float4 v = ((const float4*)x)[i4];
    unsigned int lo = (unsigned int)f2bf(v.x) | ((unsigned int)f2bf(v.y) << 16);
    unsigned int hi = (unsigned int)f2bf(v.z) | ((unsigned int)f2bf(v.w) << 16);
    ((uint2*)xb)[i4] = make_uint2(lo, hi);
}

// W (K,N) f32 -> WT (N,K) bf16
__global__ __launch_bounds__(256) void transp_w(const float* __restrict__ W,
                                                unsigned short* __restrict__ WT,
                                                int K, int N) {
    __shared__ float tile[32][33];
    int kb = blockIdx.y * 32, nb = blockIdx.x * 32;
    int tx = threadIdx.x & 31, ty = threadIdx.x >> 5;   // ty 0..7
#pragma unroll
    for (int j = 0; j < 4; ++j)
        tile[ty + 8*j][tx] = W[(size_t)(kb + ty + 8*j) * N + nb + tx];
    __syncthreads();
#pragma unroll
    for (int j = 0; j < 4; ++j) {
        int nl = ty + 8*j;
        WT[(size_t)(nb + nl) * K + kb + tx] = f2bf(tile[tx][nl]);
    }
}

// ---------------- 256x256 pipelined GEMM (A bf16 MxK, BT bf16 NxK) ----------------
// 8 waves (512 thr), BK=32, 4-slot LDS ring (128KB), counted vmcnt(8),
// XOR-swizzled LDS (inverse-swizzled global source + swizzled ds_read).
// MODE 0: qkv epilogue (feature map, split to q/k/v (B,H,L,E) bf16)
// MODE 1: f32 output + bias

template<int MODE, int KDIM, int NDIM>
__global__ __launch_bounds__(512, 2) void gemm256(
    const unsigned short* __restrict__ A,
    const unsigned short* __restrict__ BT,
    const float* __restrict__ bias,
    float* __restrict__ outF,
    unsigned short* __restrict__ qf,
    unsigned short* __restrict__ kf,
    unsigned short* __restrict__ vf)
{
    __shared__ __align__(16) unsigned short smem[65536];   // 128 KB ring: 4 x (A 8192 | B 8192)

    const int t = threadIdx.x, lane = t & 63, w = t >> 6;
    const int wr = w >> 2, wc = w & 3;                      // 2 x 4 wave grid
    const int m0 = blockIdx.y * 256, n0 = blockIdx.x * 256;
    const int lr = lane & 15, lg = lane >> 4;

    // staging chunks: chunk c = i*512+t covers LDS 16B chunk c -> row c>>2, slot c&3
    // inverse swizzle on SOURCE: data at phys slot s comes from logical col ((s ^ sw(row))<<3)
    int srow[2], scol[2];
#pragma unroll
    for (int i = 0; i < 2; ++i) {
        int c = i * 512 + t;
        int row = c >> 2, s = c & 3;
        srow[i] = row;
        scol[i] = ((s ^ ((row >> 1) & 3)) << 3);
    }

    f32x4 acc[8][4] = {};

    auto stage = [&](int T) {
        unsigned short* Ab = smem + (T & 3) * 16384;
        unsigned short* Bb = Ab + 8192;
        int kt = T * 32;
#pragma unroll
        for (int i = 0; i < 2; ++i) {
            gload_lds16(A  + (size_t)(m0 + srow[i]) * KDIM + kt + scol[i], &Ab[(i*512 + t) * 8]);
            gload_lds16(BT + (size_t)(n0 + srow[i]) * KDIM + kt + scol[i], &Bb[(i*512 + t) * 8]);
        }
    };

    auto compute = [&](int T) {
        const unsigned short* Ab = smem + (T & 3) * 16384;
        const unsigned short* Bb = Ab + 8192;
        bf16x8 af[8], bfr[4];
#pragma unroll
        for (int n = 0; n < 4; ++n) {
            int row = wc * 64 + n * 16 + lr;
            bfr[n] = *(const bf16x8*)&Bb[row * 32 + ((lg ^ ((row >> 1) & 3)) << 3)];
        }
#pragma unroll
        for (int m = 0; m < 8; ++m) {
            int row = wr * 128 + m * 16 + lr;
            af[m] = *(const bf16x8*)&Ab[row * 32 + ((lg ^ ((row >> 1) & 3)) << 3)];
        }
        __builtin_amdgcn_s_setprio(1);
#pragma unroll
        for (int m = 0; m < 8; ++m)
#pragma unroll
            for (int n = 0; n < 4; ++n)
                acc[m][n] = __builtin_amdgcn_mfma_f32_16x16x32_bf16(af[m], bfr[n], acc[m][n], 0, 0, 0);
        __builtin_amdgcn_s_setprio(0);
    };

    constexpr int NT = KDIM / 32;                 // 32
    stage(0); stage(1); stage(2);
    asm volatile("s_waitcnt vmcnt(8)" ::: "memory");     // tile 0 landed
    __builtin_amdgcn_s_barrier();
    __builtin_amdgcn_sched_barrier(0);

    for (int T = 0; T <= NT - 4; ++T) {
        stage(T + 3);                                    // 4 loads -> in flight: T+1,T+2,T+3
        compute(T);
        asm volatile("s_waitcnt vmcnt(8)" ::: "memory"); // tile T+1 landed
        __builtin_amdgcn_s_barrier();
        __builtin_amdgcn_sched_barrier(0);
    }
    compute(NT - 3);
    asm volatile("s_waitcnt vmcnt(4)" ::: "memory");     // tile NT-2 landed
    __builtin_amdgcn_s_barrier();
    __builtin_amdgcn_sched_barrier(0);
    compute(NT - 2);
    asm volatile("s_waitcnt vmcnt(0)" ::: "memory");     // tile NT-1 landed
    __builtin_amdgcn_s_barrier();
    __builtin_amdgcn_sched_barrier(0);
    compute(NT - 1);
    __syncthreads();                                     // LDS reuse below

    // ---------------- epilogues (LDS-routed, coalesced stores) ----------------
    if (MODE == 0) {
        unsigned short* cbf = smem;                      // [128][264] bf16 per pass
        const bool isQ = (n0 < D_), isK = (n0 >= D_ && n0 < 2*D_);
        const float scale = isQ ? 0.125f : 1.0f;
        unsigned short* buf = isQ ? qf : (isK ? kf : vf);
        const int b = m0 >> 12, l0 = m0 & 4095;
        const int h0 = (n0 & 1023) >> 6;
#pragma unroll
        for (int p = 0; p < 2; ++p) {
            if (wr == p) {
#pragma unroll
                for (int n = 0; n < 4; ++n) {
                    int cl = wc*64 + n*16 + lr;
                    float bv = bias[n0 + cl];
#pragma unroll
                    for (int m = 0; m < 8; ++m)
#pragma unroll
                        for (int q = 0; q < 4; ++q) {
                            int rl = m*16 + lg*4 + q;
                            float val = (acc[m][n][q] + bv) * scale;
                            float fv = (MODE == 0 && !isQ && !isK)
                                       ? val
                                       : ((val > 0.f ? val : __expf(val) - 1.f) + EPS_FEAT);
                            if (!isQ && !isK) fv = val;   // v: identity
                            cbf[rl * 264 + cl] = f2bf(fv);
                        }
                }
            }
            __syncthreads();
#pragma unroll
            for (int hh = 0; hh < 4; ++hh) {
                unsigned short* dst = buf + (((size_t)(b * H_ + h0 + hh)) * L_ + l0 + p*128) * E_;
#pragma unroll
                for (int i = 0; i < 2; ++i) {
                    int c = i*512 + t, row = c >> 3, ch = c & 7;
                    uint4 v = *(const uint4*)&cbf[row * 264 + hh*64 + ch*8];
                    *(uint4*)&dst[row * 64 + ch*8] = v;
                }
            }
            __syncthreads();
        }
    } else {
        float* cfl = (float*)smem;                       // [64][260] f32 per pass
#pragma unroll
        for (int p = 0; p < 4; ++p) {
            if (wr == (p >> 1)) {
                int mbase = (p & 1) * 4;
#pragma unroll
                for (int n = 0; n < 4; ++n) {
                    int cl = wc*64 + n*16 + lr;
                    float bv = bias[n0 + cl];
#pragma unroll
                    for (int mm = 0; mm < 4; ++mm)
#pragma unroll
                        for (int q = 0; q < 4; ++q) {
                            int rl = mm*16 + lg*4 + q;
                            cfl[rl * 260 + cl] = acc[mbase + mm][n][q] + bv;
                        }
                }
            }
            __syncthreads();
#pragma unroll
            for (int i = 0; i < 8; ++i) {
                int c = i*512 + t, row = c >> 6, ch = c & 63;
                float4 v = *(const float4*)&cfl[row * 260 + ch*4];
                *(float4*)&outF[(size_t)(m0 + p*64 + row) * NDIM + n0 + ch*4] = v;
            }
            __syncthreads();
        }
    }
}

// ---------------- chunk KV: KV_c[e][f] = sum_l K[l][e] V[l][f], ksum_c[e] ----------------

__global__ __launch_bounds__(256) void chunk_kv(
    const unsigned short* __restrict__ kf, const unsigned short* __restrict__ vf,
    float* __restrict__ kvout, float* __restrict__ ksout)
{
    constexpr int LDK = 136;                 // 128 + 8 pad
    __shared__ unsigned short Kt[64 * LDK];  // K^T : [e][l]
    __shared__ unsigned short Vt[80 * LDK];  // V^T : [f][l], row 64 = ones (ksum trick)

    int t = threadIdx.x, lane = t & 63, w = t >> 6;
    int bid = blockIdx.x;                    // bh*NC + c
    const unsigned short* kp = kf + (size_t)bid * CHK * E_;
    const unsigned short* vp = vf + (size_t)bid * CHK * E_;

#pragma unroll
    for (int it = 0; it < 4; ++it) {
        int s = it * 256 + t;                // 0..1023  (16B granules of 128x64)
        int rl = s >> 3, e0 = (s & 7) << 3;
        uint4 kv8 = *(const uint4*)(kp + s * 8);
        uint4 vv8 = *(const uint4*)(vp + s * 8);
        unsigned int kw[4] = {kv8.x, kv8.y, kv8.z, kv8.w};
        unsigned int vw[4] = {vv8.x, vv8.y, vv8.z, vv8.w};
#pragma unroll
        for (int jw = 0; jw < 4; ++jw) {
            Kt[(e0 + 2*jw    ) * LDK + rl] = (unsigned short)(kw[jw] & 0xFFFF);
            Kt[(e0 + 2*jw + 1) * LDK + rl] = (unsigned short)(kw[jw] >> 16);
            Vt[(e0 + 2*jw    ) * LDK + rl] = (unsigned short)(vw[jw] & 0xFFFF);
            Vt[(e0 + 2*jw + 1) * LDK + rl] = (unsigned short)(vw[jw] >> 16);
        }
    }
    if (t < 128) Vt[64 * LDK + t] = 0x3F80;  // bf16 1.0
    for (int i = t; i < 15 * LDK; i += 256) Vt[65 * LDK + i] = 0;
    __syncthreads();

    int lr = lane & 15, lg = lane >> 4;
    f32x4 acc[5] = {};
#pragma unroll
    for (int ks = 0; ks < 4; ++ks) {
        bf16x8 a = *(const bf16x8*)&Kt[(w*16 + lr) * LDK + ks*32 + lg*8];
#pragma unroll
        for (int n = 0; n < 5; ++n) {
            bf16x8 b = *(const bf16x8*)&Vt[(n*16 + lr) * LDK + ks*32 + lg*8];
            acc[n] = __builtin_amdgcn_mfma_f32_16x16x32_bf16(a, b, acc[n], 0, 0, 0);
        }
    }
    float* kvo = kvout + (size_t)bid * E_ * E_;
#pragma unroll
    for (int n = 0; n < 4; ++n)
#pragma unroll
        for (int q = 0; q < 4; ++q) {
            int e = w*16 + lg*4 + q, f = n*16 + lr;
            kvo[e * 64 + f] = acc[n][q];
        }
    if (lr == 0) {
#pragma unroll
        for (int q = 0; q < 4; ++q) {
            int e = w*16 + lg*4 + q;
            ksout[(size_t)bid * 64 + e] = acc[4][q];
        }
    }
}

// ---------------- exclusive prefix over chunks (per bh) ----------------

__global__ __launch_bounds__(256) void prefix_kv(float* __restrict__ kv, float* __restrict__ ks) {
    int bh = blockIdx.y, part = blockIdx.x, t = threadIdx.x;
    float st[4];
#pragma unroll
    for (int j = 0; j < 4; ++j) st[j] = 0.f;
    for (int c = 0; c < NC; ++c) {
        float* p = kv + ((size_t)bh * NC + c) * 4096 + part * 1024;
#pragma unroll
        for (int j = 0; j < 4; ++j) {
            float tmp = p[j * 256 + t];
            p[j * 256 + t] = st[j];
            st[j] += tmp;
        }
    }
    if (part == 0 && t < 64) {
        float s0 = 0.f;
        for (int c = 0; c < NC; ++c) {
            float* p = ks + ((size_t)bh * NC + c) * 64;
            float tmp = p[t]; p[t] = s0; s0 += tmp;
        }
    }
}

// ---------------- attention output per (bh, chunk) ----------------

__global__ __launch_bounds__(256) void attn_out(
    const unsigned short* __restrict__ qf, const unsigned short* __restrict__ kf,
    const unsigned short* __restrict__ vf, const float* __restrict__ kvst,
    const float* __restrict__ ksst, unsigned short* __restrict__ attn)
{
    constexpr int LQ = 72;    // Q/K stride (64+8)
    constexpr int LV = 136;   // Vt & S stride (128+8)
    constexpr int LKV = 72;   // KVt stride (64+8)
    __shared__ unsigned short Qs[128 * LQ];
    __shared__ unsigned short Ks[128 * LQ];
    __shared__ unsigned short Vt[80 * LV];    // row 64 = ones
    __shared__ unsigned short KVt[80 * LKV];  // row 64 = ksum
    __shared__ unsigned short Ss[128 * LV];

    int t = threadIdx.x, lane = t & 63, w = t >> 6;
    int bid = blockIdx.x;
    int bh = bid >> 5, c = bid & 31;
    const unsigned short* qp = qf + (size_t)bid * CHK * E_;
    const unsigned short* kp = kf + (size_t)bid * CHK * E_;
    const unsigned short* vp = vf + (size_t)bid * CHK * E_;

#pragma unroll
    for (int it = 0; it < 4; ++it) {
        int s = it * 256 + t;
        int r = s >> 3, e0 = (s & 7) << 3;
        uint4 qv = *(const uint4*)(qp + s * 8);
        uint4 kv = *(const uint4*)(kp + s * 8);
        uint4 vv = *(const uint4*)(vp + s * 8);
        *(uint4*)&Qs[r * LQ + e0] = qv;
        *(uint4*)&Ks[r * LQ + e0] = kv;
        unsigned int vw[4] = {vv.x, vv.y, vv.z, vv.w};
#pragma unroll
        for (int jw = 0; jw < 4; ++jw) {
            Vt[(e0 + 2*jw    ) * LV + r] = (unsigned short)(vw[jw] & 0xFFFF);
            Vt[(e0 + 2*jw + 1) * LV + r] = (unsigned short)(vw[jw] >> 16);
        }
    }
    const float* kvp = kvst + (size_t)bid * 4096;
#pragma unroll
    for (int it = 0; it < 16; ++it) {
        int idx = it * 256 + t;
        int e = idx >> 6, f = idx & 63;
        KVt[f * LKV + e] = f2bf(kvp[idx]);
    }
    if (t < 64)  KVt[64 * LKV + t] = f2bf(ksst[(size_t)bid * 64 + t]);
    if (t < 128) Vt[64 * LV + t] = 0x3F80;
    for (int i = t; i < 15 * LV;  i += 256) Vt[65 * LV  + i] = 0;
    for (int i = t; i < 15 * LKV; i += 256) KVt[65 * LKV + i] = 0;
    __syncthreads();

    int lr = lane & 15, lg = lane >> 4;

    // S-phase: wave w owns rows [w*32, w*32+32)
#pragma unroll
    for (int m = 0; m < 2; ++m) {
        int rbase = w * 32 + m * 16;
        bf16x8 aq0 = *(const bf16x8*)&Qs[(rbase + lr) * LQ + lg*8];
        bf16x8 aq1 = *(const bf16x8*)&Qs[(rbase + lr) * LQ + 32 + lg*8];
        int jmax = 2 * w + m;
        for (int jb = 0; jb < 8; ++jb) {
            if (jb <= jmax) {
                f32x4 sacc = {};
                bf16x8 b0 = *(const bf16x8*)&Ks[(jb*16 + lr) * LQ + lg*8];
                bf16x8 b1 = *(const bf16x8*)&Ks[(jb*16 + lr) * LQ + 32 + lg*8];
                sacc = __builtin_amdgcn_mfma_f32_16x16x32_bf16(aq0, b0, sacc, 0, 0, 0);
                sacc = __builtin_amdgcn_mfma_f32_16x16x32_bf16(aq1, b1, sacc, 0, 0, 0);
#pragma unroll
                for (int q = 0; q < 4; ++q) {
                    int r = rbase + lg*4 + q;
                    int j = jb*16 + lr;
                    Ss[r * LV + j] = (j <= r) ? f2bf(sacc[q]) : (unsigned short)0;
                }
            } else {
#pragma unroll
                for (int q = 0; q < 4; ++q) {
                    int r = rbase + lg*4 + q;
                    Ss[r * LV + jb*16 + lr] = 0;
                }
            }
        }
    }
    // no barrier needed: each wave reads only its own S rows below

    f32x4 oacc[2][5] = {};
#pragma unroll
    for (int m = 0; m < 2; ++m) {
        int rbase = w * 32 + m * 16;
        // inter-chunk: Q @ KV_state (K-dim 64)
#pragma unroll
        for (int ks = 0; ks < 2; ++ks) {
            bf16x8 a = *(const bf16x8*)&Qs[(rbase + lr) * LQ + ks*32 + lg*8];
#pragma unroll
            for (int n = 0; n < 5; ++n) {
                bf16x8 b = *(const bf16x8*)&KVt[(n*16 + lr) * LKV + ks*32 + lg*8];
                oacc[m][n] = __builtin_amdgcn_mfma_f32_16x16x32_bf16(a, b, oacc[m][n], 0, 0, 0);
            }
        }
        // intra-chunk: S @ V  (only k-blocks <= w are nonzero)
        for (int ks = 0; ks <= w; ++ks) {
            bf16x8 a = *(const bf16x8*)&Ss[(rbase + lr) * LV + ks*32 + lg*8];
#pragma unroll
            for (int n = 0; n < 5; ++n) {
                bf16x8 b = *(const bf16x8*)&Vt[(n*16 + lr) * LV + ks*32 + lg*8];
                oacc[m][n] = __builtin_amdgcn_mfma_f32_16x16x32_bf16(a, b, oacc[m][n], 0, 0, 0);
            }
        }
    }

    // den broadcast (col 64 lives in lanes with lr==0) + normalize + store
    int b_idx = bh >> 4, h_idx = bh & 15;
#pragma unroll
    for (int m = 0; m < 2; ++m) {
        int rbase = w * 32 + m * 16;
        float den[4];
#pragma unroll
        for (int q = 0; q < 4; ++q)
            den[q] = __shfl(oacc[m][4][q], lane & 48, 64) + EPS_DEN;
#pragma unroll
        for (int n = 0; n < 4; ++n) {
#pragma unroll
            for (int q = 0; q < 4; ++q) {
                int r = rbase + lg*4 + q;
                int lpos = c * CHK + r;
                int col = n*16 + lr;
                size_t dst = ((size_t)b_idx * L_ + lpos) * D_ + h_idx * 64 + col;
                attn[dst] = f2bf(oacc[m][n][q] / den[q]);
            }
        }
    }
}

// ---------------- launcher ----------------

extern "C" void kernel_launch(void* const* d_in, const int* in_sizes, int n_in,
                              void* d_out, int out_size, void* d_ws, size_t ws_size,
                              hipStream_t stream)
{
    const float* x    = (const float*)d_in[0];
    const float* Wqkv = (const float*)d_in[1];
    const float* bqkv = (const float*)d_in[2];
    const float* Wout = (const float*)d_in[3];
    const float* bout = (const float*)d_in[4];
    float* out = (float*)d_out;

    char* ws = (char*)d_ws;
    size_t off = 0;
    auto alloc = [&](size_t bytes) { void* p = ws + off; off += (bytes + 255) & ~(size_t)255; return p; };
    unsigned short* xb  = (unsigned short*)alloc((size_t)M_ * D_ * 2);
    unsigned short* WqT = (unsigned short*)alloc((size_t)N1_ * D_ * 2);
    unsigned short* WoT = (unsigned short*)alloc((size_t)D_ * D_ * 2);
    unsigned short* qfb = (unsigned short*)alloc((size_t)M_ * D_ * 2);
    unsigned short* kfb = (unsigned short*)alloc((size_t)M_ * D_ * 2);
    unsigned short* vfb = (unsigned short*)alloc((size_t)M_ * D_ * 2);
    float* kvw = (float*)alloc((size_t)BH * NC * E_ * E_ * 4);
    float* ksw = (float*)alloc((size_t)BH * NC * E_ * 4);
    unsigned short* attn = xb;   // alias: x_bf16 is dead after gemm1

    cvt_x<<<(M_ * D_ / 4) / 256, 256, 0, stream>>>(x, xb);
    transp_w<<<dim3(N1_ / 32, D_ / 32), 256, 0, stream>>>(Wqkv, WqT, D_, N1_);
    transp_w<<<dim3(D_ / 32, D_ / 32), 256, 0, stream>>>(Wout, WoT, D_, D_);

    gemm256<0, D_, N1_><<<dim3(N1_ / 256, M_ / 256), 512, 0, stream>>>(
        xb, WqT, bqkv, nullptr, qfb, kfb, vfb);

    chunk_kv<<<BH * NC, 256, 0, stream>>>(kfb, vfb, kvw, ksw);
    prefix_kv<<<dim3(4, BH), 256, 0, stream>>>(kvw, ksw);
    attn_out<<<BH * NC, 256, 0, stream>>>(qfb, kfb, vfb, kvw, ksw, attn);

    gemm256<1, D_, D_><<<dim3(D_ / 256, M_ / 256), 512, 0, stream>>>(
        attn, WoT, bout, out, nullptr, nullptr, nullptr);
}

// Round 6
// 282.447 us; speedup vs baseline: 1.2667x; 1.0169x over previous
//
#include <hip/hip_runtime.h>
#include <hip/hip_bf16.h>
#include <stdint.h>

#define B_ 4
#define L_ 4096
#define D_ 1024
#define H_ 16
#define E_ 64
#define M_ (B_*L_)       // 16384 rows
#define N1_ (3*D_)       // 3072
#define CHK 128
#define NC (L_/CHK)      // 32
#define BH (B_*H_)       // 64

#define EPS_FEAT 1.0001f
#define EPS_DEN 1e-6f

typedef __attribute__((ext_vector_type(4))) float f32x4;
typedef __attribute__((ext_vector_type(8))) short bf16x8;

__device__ __forceinline__ unsigned short f2bf(float x) {
    union { float f; unsigned int u; } v; v.f = x;
    unsigned int r = v.u + 0x7FFFu + ((v.u >> 16) & 1u);
    return (unsigned short)(r >> 16);
}

// async global->LDS, 16B per lane. LDS dest = wave-uniform base + lane*16.
__device__ __forceinline__ void gload_lds16(const unsigned short* g, unsigned short* l) {
    __builtin_amdgcn_global_load_lds(
        (const __attribute__((address_space(1))) unsigned int*)(const void*)g,
        (__attribute__((address_space(3))) unsigned int*)(void*)l,
        16, 0, 0);
}

// ---------------- prep kernels ----------------

__global__ __launch_bounds__(256) void cvt_x(const float* __restrict__ x,
                                             unsigned short* __restrict__ xb) {
    int i4 = blockIdx.x * 256 + threadIdx.x;      // float4 index
    float4 v = ((const float4*)x)[i4];
    unsigned int lo = (unsigned int)f2bf(v.x) | ((unsigned int)f2bf(v.y) << 16);
    unsigned int hi = (unsigned int)f2bf(v.z) | ((unsigned int)f2bf(v.w) << 16);
    ((uint2*)xb)[i4] = make_uint2(lo, hi);
}

// W (K,N) f32 -> WT (N,K) bf16
__global__ __launch_bounds__(256) void transp_w(const float* __restrict__ W,
                                                unsigned short* __restrict__ WT,
                                                int K, int N) {
    __shared__ float tile[32][33];
    int kb = blockIdx.y * 32, nb = blockIdx.x * 32;
    int tx = threadIdx.x & 31, ty = threadIdx.x >> 5;   // ty 0..7
#pragma unroll
    for (int j = 0; j < 4; ++j)
        tile[ty + 8*j][tx] = W[(size_t)(kb + ty + 8*j) * N + nb + tx];
    __syncthreads();
#pragma unroll
    for (int j = 0; j < 4; ++j) {
        int nl = ty + 8*j;
        WT[(size_t)(nb + nl) * K + kb + tx] = f2bf(tile[tx][nl]);
    }
}

// ---------------- 256x256 pipelined GEMM (A bf16 MxK, BT bf16 NxK) ----------------
// 8 waves (512 thr), BK=32, 4-slot LDS ring (128KB), counted vmcnt(8),
// 2 phases per K-tile (m-halves), XCD-chunked block swizzle.

template<int MODE, int KDIM, int NDIM>
__global__ __launch_bounds__(512, 2) void gemm256(
    const unsigned short* __restrict__ A,
    const unsigned short* __restrict__ BT,
    const float* __restrict__ bias,
    float* __restrict__ outF,
    unsigned short* __restrict__ qf,
    unsigned short* __restrict__ kf,
    unsigned short* __restrict__ vf)
{
    __shared__ __align__(16) unsigned short smem[65536];   // 128 KB ring: 4 x (A 8192 | B 8192)

    const int t = threadIdx.x, lane = t & 63, w = t >> 6;
    const int wr = w >> 2, wc = w & 3;                      // 2 x 4 wave grid

    // XCD-chunked bijective swizzle (nwg % 8 == 0 for both modes)
    const int nwgx = NDIM / 256;
    const int nwg = nwgx * (M_ / 256);
    const int bid0 = blockIdx.y * nwgx + blockIdx.x;
    const int swz = (bid0 & 7) * (nwg >> 3) + (bid0 >> 3);
    const int m0 = (swz / nwgx) * 256, n0 = (swz % nwgx) * 256;
    const int lr = lane & 15, lg = lane >> 4;

    // staging chunks: chunk c = i*512+t covers LDS 16B chunk c -> row c>>2, slot c&3
    // inverse swizzle on SOURCE: phys slot s holds logical col ((s ^ sw(row))<<3)
    int srow[2], scol[2];
#pragma unroll
    for (int i = 0; i < 2; ++i) {
        int c = i * 512 + t;
        int row = c >> 2, s = c & 3;
        srow[i] = row;
        scol[i] = ((s ^ ((row >> 1) & 3)) << 3);
    }

    f32x4 acc[8][4] = {};

    auto stageHalf = [&](int T, int half) {                 // half 0: A, half 1: B
        unsigned short* base = smem + (T & 3) * 16384 + half * 8192;
        const unsigned short* src = half ? BT : A;
        const int boff = half ? n0 : m0;
        const int kt = T * 32;
#pragma unroll
        for (int i = 0; i < 2; ++i)
            gload_lds16(src + (size_t)(boff + srow[i]) * KDIM + kt + scol[i],
                        &base[(i*512 + t) * 8]);
    };

    auto tile = [&](int T, bool doStage) {
        const unsigned short* Ab = smem + (T & 3) * 16384;
        const unsigned short* Bb = Ab + 8192;
        bf16x8 af[4], bfr[4];
        // ---- phase A: m-half 0 + all B frags ----
#pragma unroll
        for (int n = 0; n < 4; ++n) {
            int row = wc * 64 + n * 16 + lr;
            bfr[n] = *(const bf16x8*)&Bb[row * 32 + ((lg ^ ((row >> 1) & 3)) << 3)];
        }
#pragma unroll
        for (int m = 0; m < 4; ++m) {
            int row = wr * 128 + m * 16 + lr;
            af[m] = *(const bf16x8*)&Ab[row * 32 + ((lg ^ ((row >> 1) & 3)) << 3)];
        }
        if (doStage) stageHalf(T + 3, 0);
        __builtin_amdgcn_s_barrier();
        asm volatile("s_waitcnt lgkmcnt(0)" ::: "memory");
        __builtin_amdgcn_sched_barrier(0);
        __builtin_amdgcn_s_setprio(1);
#pragma unroll
        for (int m = 0; m < 4; ++m)
#pragma unroll
            for (int n = 0; n < 4; ++n)
                acc[m][n] = __builtin_amdgcn_mfma_f32_16x16x32_bf16(af[m], bfr[n], acc[m][n], 0, 0, 0);
        __builtin_amdgcn_s_setprio(0);
        // ---- phase B: m-half 1 (B frags reused from regs) ----
#pragma unroll
        for (int m = 0; m < 4; ++m) {
            int row = wr * 128 + (m + 4) * 16 + lr;
            af[m] = *(const bf16x8*)&Ab[row * 32 + ((lg ^ ((row >> 1) & 3)) << 3)];
        }
        if (doStage) stageHalf(T + 3, 1);
        __builtin_amdgcn_s_barrier();
        asm volatile("s_waitcnt lgkmcnt(0)" ::: "memory");
        __builtin_amdgcn_sched_barrier(0);
        __builtin_amdgcn_s_setprio(1);
#pragma unroll
        for (int m = 0; m < 4; ++m)
#pragma unroll
            for (int n = 0; n < 4; ++n)
                acc[m + 4][n] = __builtin_amdgcn_mfma_f32_16x16x32_bf16(af[m], bfr[n], acc[m + 4][n], 0, 0, 0);
        __builtin_amdgcn_s_setprio(0);
    };

    constexpr int NT = KDIM / 32;                 // 32
    stageHalf(0,0); stageHalf(0,1);
    stageHalf(1,0); stageHalf(1,1);
    stageHalf(2,0); stageHalf(2,1);
    asm volatile("s_waitcnt vmcnt(8)" ::: "memory");     // tile 0 landed
    __builtin_amdgcn_s_barrier();
    __builtin_amdgcn_sched_barrier(0);

    for (int T = 0; T <= NT - 4; ++T) {
        tile(T, true);                                   // in flight after: T+1,T+2,T+3
        asm volatile("s_waitcnt vmcnt(8)" ::: "memory"); // tile T+1 landed
        __builtin_amdgcn_s_barrier();
        __builtin_amdgcn_sched_barrier(0);
    }
    tile(NT - 3, false);
    asm volatile("s_waitcnt vmcnt(4)" ::: "memory");     // tile NT-2 landed
    __builtin_amdgcn_s_barrier();
    __builtin_amdgcn_sched_barrier(0);
    tile(NT - 2, false);
    asm volatile("s_waitcnt vmcnt(0)" ::: "memory");     // tile NT-1 landed
    __builtin_amdgcn_s_barrier();
    __builtin_amdgcn_sched_barrier(0);
    tile(NT - 1, false);
    __syncthreads();                                     // LDS reuse below

    // ---------------- epilogues (LDS-routed, coalesced stores) ----------------
    if (MODE == 0) {
        unsigned short* cbf = smem;                      // [128][264] bf16 per pass
        const bool isQ = (n0 < D_), isK = (n0 >= D_ && n0 < 2*D_);
        const float scale = isQ ? 0.125f : 1.0f;
        unsigned short* buf = isQ ? qf : (isK ? kf : vf);
        const int b = m0 >> 12, l0 = m0 & 4095;
        const int h0 = (n0 & 1023) >> 6;
#pragma unroll
        for (int p = 0; p < 2; ++p) {
            if (wr == p) {
#pragma unroll
                for (int n = 0; n < 4; ++n) {
                    int cl = wc*64 + n*16 + lr;
                    float bv = bias[n0 + cl];
#pragma unroll
                    for (int m = 0; m < 8; ++m)
#pragma unroll
                        for (int q = 0; q < 4; ++q) {
                            int rl = m*16 + lg*4 + q;
                            float val = (acc[m][n][q] + bv) * scale;
                            float fv = (isQ || isK)
                                       ? ((val > 0.f ? val : __expf(val) - 1.f) + EPS_FEAT)
                                       : val;
                            cbf[rl * 264 + cl] = f2bf(fv);
                        }
                }
            }
            __syncthreads();
#pragma unroll
            for (int hh = 0; hh < 4; ++hh) {
                unsigned short* dst = buf + (((size_t)(b * H_ + h0 + hh)) * L_ + l0 + p*128) * E_;
#pragma unroll
                for (int i = 0; i < 2; ++i) {
                    int c = i*512 + t, row = c >> 3, ch = c & 7;
                    uint4 v = *(const uint4*)&cbf[row * 264 + hh*64 + ch*8];
                    *(uint4*)&dst[row * 64 + ch*8] = v;
                }
            }
            __syncthreads();
        }
    } else {
        float* cfl = (float*)smem;                       // [64][260] f32 per pass
#pragma unroll
        for (int p = 0; p < 4; ++p) {
            if (wr == (p >> 1)) {
                int mbase = (p & 1) * 4;
#pragma unroll
                for (int n = 0; n < 4; ++n) {
                    int cl = wc*64 + n*16 + lr;
                    float bv = bias[n0 + cl];
#pragma unroll
                    for (int mm = 0; mm < 4; ++mm)
#pragma unroll
                        for (int q = 0; q < 4; ++q) {
                            int rl = mm*16 + lg*4 + q;
                            cfl[rl * 260 + cl] = acc[mbase + mm][n][q] + bv;
                        }
                }
            }
            __syncthreads();
#pragma unroll
            for (int i = 0; i < 8; ++i) {
                int c = i*512 + t, row = c >> 6, ch = c & 63;
                float4 v = *(const float4*)&cfl[row * 260 + ch*4];
                *(float4*)&outF[(size_t)(m0 + p*64 + row) * NDIM + n0 + ch*4] = v;
            }
            __syncthreads();
        }
    }
}

// ---------------- chunk KV: KV_c[e][f] = sum_l K[l][e] V[l][f], ksum_c[e] ----------------

__global__ __launch_bounds__(256) void chunk_kv(
    const unsigned short* __restrict__ kf, const unsigned short* __restrict__ vf,
    float* __restrict__ kvout, float* __restrict__ ksout)
{
    constexpr int LDK = 136;                 // 128 + 8 pad
    __shared__ unsigned short Kt[64 * LDK];  // K^T : [e][l]
    __shared__ unsigned short Vt[80 * LDK];  // V^T : [f][l], row 64 = ones (ksum trick)

    int t = threadIdx.x, lane = t & 63, w = t >> 6;
    int bid = blockIdx.x;                    // bh*NC + c
    const unsigned short* kp = kf + (size_t)bid * CHK * E_;
    const unsigned short* vp = vf + (size_t)bid * CHK * E_;

#pragma unroll
    for (int it = 0; it < 4; ++it) {
        int s = it * 256 + t;                // 0..1023  (16B granules of 128x64)
        int rl = s >> 3, e0 = (s & 7) << 3;
        uint4 kv8 = *(const uint4*)(kp + s * 8);
        uint4 vv8 = *(const uint4*)(vp + s * 8);
        unsigned int kw[4] = {kv8.x, kv8.y, kv8.z, kv8.w};
        unsigned int vw[4] = {vv8.x, vv8.y, vv8.z, vv8.w};
#pragma unroll
        for (int jw = 0; jw < 4; ++jw) {
            Kt[(e0 + 2*jw    ) * LDK + rl] = (unsigned short)(kw[jw] & 0xFFFF);
            Kt[(e0 + 2*jw + 1) * LDK + rl] = (unsigned short)(kw[jw] >> 16);
            Vt[(e0 + 2*jw    ) * LDK + rl] = (unsigned short)(vw[jw] & 0xFFFF);
            Vt[(e0 + 2*jw + 1) * LDK + rl] = (unsigned short)(vw[jw] >> 16);
        }
    }
    if (t < 128) Vt[64 * LDK + t] = 0x3F80;  // bf16 1.0
    for (int i = t; i < 15 * LDK; i += 256) Vt[65 * LDK + i] = 0;
    __syncthreads();

    int lr = lane & 15, lg = lane >> 4;
    f32x4 acc[5] = {};
#pragma unroll
    for (int ks = 0; ks < 4; ++ks) {
        bf16x8 a = *(const bf16x8*)&Kt[(w*16 + lr) * LDK + ks*32 + lg*8];
#pragma unroll
        for (int n = 0; n < 5; ++n) {
            bf16x8 b = *(const bf16x8*)&Vt[(n*16 + lr) * LDK + ks*32 + lg*8];
            acc[n] = __builtin_amdgcn_mfma_f32_16x16x32_bf16(a, b, acc[n], 0, 0, 0);
        }
    }
    float* kvo = kvout + (size_t)bid * E_ * E_;
#pragma unroll
    for (int n = 0; n < 4; ++n)
#pragma unroll
        for (int q = 0; q < 4; ++q) {
            int e = w*16 + lg*4 + q, f = n*16 + lr;
            kvo[e * 64 + f] = acc[n][q];
        }
    if (lr == 0) {
#pragma unroll
        for (int q = 0; q < 4; ++q) {
            int e = w*16 + lg*4 + q;
            ksout[(size_t)bid * 64 + e] = acc[4][q];
        }
    }
}

// ---------------- exclusive prefix over chunks (per bh), bf16 output ----------------

__global__ __launch_bounds__(256) void prefix_kv(
    const float* __restrict__ kv, const float* __restrict__ ks,
    unsigned short* __restrict__ kvb, unsigned short* __restrict__ ksb)
{
    int bh = blockIdx.y, part = blockIdx.x, t = threadIdx.x;
    float st[4];
#pragma unroll
    for (int j = 0; j < 4; ++j) st[j] = 0.f;
    for (int c = 0; c < NC; ++c) {
        const float* p = kv + ((size_t)bh * NC + c) * 4096 + part * 1024;
        unsigned short* q = kvb + ((size_t)bh * NC + c) * 4096 + part * 1024;
#pragma unroll
        for (int j = 0; j < 4; ++j) {
            float tmp = p[j * 256 + t];
            q[j * 256 + t] = f2bf(st[j]);
            st[j] += tmp;
        }
    }
    if (part == 0 && t < 64) {
        float s0 = 0.f;
        for (int c = 0; c < NC; ++c) {
            float tmp = ks[((size_t)bh * NC + c) * 64 + t];
            ksb[((size_t)bh * NC + c) * 64 + t] = f2bf(s0);
            s0 += tmp;
        }
    }
}

// ---------------- attention output per (bh, chunk) ----------------

__global__ __launch_bounds__(256) void attn_out(
    const unsigned short* __restrict__ qf, const unsigned short* __restrict__ kf,
    const unsigned short* __restrict__ vf, const unsigned short* __restrict__ kvb,
    const unsigned short* __restrict__ ksb, unsigned short* __restrict__ attn)
{
    constexpr int LQ = 72;    // Q/K stride (64+8)
    constexpr int LV = 136;   // Vt & S stride (128+8)
    constexpr int LKV = 72;   // KVt stride (64+8)
    __shared__ unsigned short Qs[128 * LQ];
    __shared__ unsigned short Ks[128 * LQ];
    __shared__ unsigned short Vt[80 * LV];    // row 64 = ones
    __shared__ unsigned short KVt[80 * LKV];  // row 64 = ksum
    __shared__ unsigned short Ss[128 * LV];

    int t = threadIdx.x, lane = t & 63, w = t >> 6;
    int bid = blockIdx.x;
    int bh = bid >> 5, c = bid & 31;
    const unsigned short* qp = qf + (size_t)bid * CHK * E_;
    const unsigned short* kp = kf + (size_t)bid * CHK * E_;
    const unsigned short* vp = vf + (size_t)bid * CHK * E_;

#pragma unroll
    for (int it = 0; it < 4; ++it) {
        int s = it * 256 + t;
        int r = s >> 3, e0 = (s & 7) << 3;
        uint4 qv = *(const uint4*)(qp + s * 8);
        uint4 kv = *(const uint4*)(kp + s * 8);
        uint4 vv = *(const uint4*)(vp + s * 8);
        *(uint4*)&Qs[r * LQ + e0] = qv;
        *(uint4*)&Ks[r * LQ + e0] = kv;
        unsigned int vw[4] = {vv.x, vv.y, vv.z, vv.w};
#pragma unroll
        for (int jw = 0; jw < 4; ++jw) {
            Vt[(e0 + 2*jw    ) * LV + r] = (unsigned short)(vw[jw] & 0xFFFF);
            Vt[(e0 + 2*jw + 1) * LV + r] = (unsigned short)(vw[jw] >> 16);
        }
    }
    const unsigned short* kvp = kvb + (size_t)bid * 4096;
#pragma unroll
    for (int it = 0; it < 16; ++it) {
        int idx = it * 256 + t;
        int e = idx >> 6, f = idx & 63;
        KVt[f * LKV + e] = kvp[idx];
    }
    if (t < 64)  KVt[64 * LKV + t] = ksb[(size_t)bid * 64 + t];
    if (t < 128) Vt[64 * LV + t] = 0x3F80;
    for (int i = t; i < 15 * LV;  i += 256) Vt[65 * LV  + i] = 0;
    for (int i = t; i < 15 * LKV; i += 256) KVt[65 * LKV + i] = 0;
    __syncthreads();

    int lr = lane & 15, lg = lane >> 4;

    // S-phase: wave w owns rows [w*32, w*32+32)
#pragma unroll
    for (int m = 0; m < 2; ++m) {
        int rbase = w * 32 + m * 16;
        bf16x8 aq0 = *(const bf16x8*)&Qs[(rbase + lr) * LQ + lg*8];
        bf16x8 aq1 = *(const bf16x8*)&Qs[(rbase + lr) * LQ + 32 + lg*8];
        int jmax = 2 * w + m;
        for (int jb = 0; jb < 8; ++jb) {
            if (jb <= jmax) {
                f32x4 sacc = {};
                bf16x8 b0 = *(const bf16x8*)&Ks[(jb*16 + lr) * LQ + lg*8];
                bf16x8 b1 = *(const bf16x8*)&Ks[(jb*16 + lr) * LQ + 32 + lg*8];
                sacc = __builtin_amdgcn_mfma_f32_16x16x32_bf16(aq0, b0, sacc, 0, 0, 0);
                sacc = __builtin_amdgcn_mfma_f32_16x16x32_bf16(aq1, b1, sacc, 0, 0, 0);
#pragma unroll
                for (int q = 0; q < 4; ++q) {
                    int r = rbase + lg*4 + q;
                    int j = jb*16 + lr;
                    Ss[r * LV + j] = (j <= r) ? f2bf(sacc[q]) : (unsigned short)0;
                }
            } else {
#pragma unroll
                for (int q = 0; q < 4; ++q) {
                    int r = rbase + lg*4 + q;
                    Ss[r * LV + jb*16 + lr] = 0;
                }
            }
        }
    }
    // no barrier needed: each wave reads only its own S rows below

    f32x4 oacc[2][5] = {};
#pragma unroll
    for (int m = 0; m < 2; ++m) {
        int rbase = w * 32 + m * 16;
        // inter-chunk: Q @ KV_state (K-dim 64)
#pragma unroll
        for (int ks = 0; ks < 2; ++ks) {
            bf16x8 a = *(const bf16x8*)&Qs[(rbase + lr) * LQ + ks*32 + lg*8];
#pragma unroll
            for (int n = 0; n < 5; ++n) {
                bf16x8 b = *(const bf16x8*)&KVt[(n*16 + lr) * LKV + ks*32 + lg*8];
                oacc[m][n] = __builtin_amdgcn_mfma_f32_16x16x32_bf16(a, b, oacc[m][n], 0, 0, 0);
            }
        }
        // intra-chunk: S @ V  (only k-blocks <= w are nonzero)
        for (int ks = 0; ks <= w; ++ks) {
            bf16x8 a = *(const bf16x8*)&Ss[(rbase + lr) * LV + ks*32 + lg*8];
#pragma unroll
            for (int n = 0; n < 5; ++n) {
                bf16x8 b = *(const bf16x8*)&Vt[(n*16 + lr) * LV + ks*32 + lg*8];
                oacc[m][n] = __builtin_amdgcn_mfma_f32_16x16x32_bf16(a, b, oacc[m][n], 0, 0, 0);
            }
        }
    }

    // den broadcast (col 64 lives in lanes with lr==0) + normalize + store
    int b_idx = bh >> 4, h_idx = bh & 15;
#pragma unroll
    for (int m = 0; m < 2; ++m) {
        int rbase = w * 32 + m * 16;
        float den[4];
#pragma unroll
        for (int q = 0; q < 4; ++q)
            den[q] = __shfl(oacc[m][4][q], lane & 48, 64) + EPS_DEN;
#pragma unroll
        for (int n = 0; n < 4; ++n) {
#pragma unroll
            for (int q = 0; q < 4; ++q) {
                int r = rbase + lg*4 + q;
                int lpos = c * CHK + r;
                int col = n*16 + lr;
                size_t dst = ((size_t)b_idx * L_ + lpos) * D_ + h_idx * 64 + col;
                attn[dst] = f2bf(oacc[m][n][q] / den[q]);
            }
        }
    }
}

// ---------------- launcher ----------------

extern "C" void kernel_launch(void* const* d_in, const int* in_sizes, int n_in,
                              void* d_out, int out_size, void* d_ws, size_t ws_size,
                              hipStream_t stream)
{
    const float* x    = (const float*)d_in[0];
    const float* Wqkv = (const float*)d_in[1];
    const float* bqkv = (const float*)d_in[2];
    const float* Wout = (const float*)d_in[3];
    const float* bout = (const float*)d_in[4];
    float* out = (float*)d_out;

    char* ws = (char*)d_ws;
    size_t off = 0;
    auto alloc = [&](size_t bytes) { void* p = ws + off; off += (bytes + 255) & ~(size_t)255; return p; };
    unsigned short* xb  = (unsigned short*)alloc((size_t)M_ * D_ * 2);
    unsigned short* WqT = (unsigned short*)alloc((size_t)N1_ * D_ * 2);
    unsigned short* WoT = (unsigned short*)alloc((size_t)D_ * D_ * 2);
    unsigned short* qfb = (unsigned short*)alloc((size_t)M_ * D_ * 2);
    unsigned short* kfb = (unsigned short*)alloc((size_t)M_ * D_ * 2);
    unsigned short* vfb = (unsigned short*)alloc((size_t)M_ * D_ * 2);
    float* kvw = (float*)alloc((size_t)BH * NC * E_ * E_ * 4);
    float* ksw = (float*)alloc((size_t)BH * NC * E_ * 4);
    unsigned short* kvb = (unsigned short*)alloc((size_t)BH * NC * E_ * E_ * 2);
    unsigned short* ksb = (unsigned short*)alloc((size_t)BH * NC * E_ * 2);
    unsigned short* attn = xb;   // alias: x_bf16 is dead after gemm<0>

    cvt_x<<<(M_ * D_ / 4) / 256, 256, 0, stream>>>(x, xb);
    transp_w<<<dim3(N1_ / 32, D_ / 32), 256, 0, stream>>>(Wqkv, WqT, D_, N1_);
    transp_w<<<dim3(D_ / 32, D_ / 32), 256, 0, stream>>>(Wout, WoT, D_, D_);

    gemm256<0, D_, N1_><<<dim3(N1_ / 256, M_ / 256), 512, 0, stream>>>(
        xb, WqT, bqkv, nullptr, qfb, kfb, vfb);

    chunk_kv<<<BH * NC, 256, 0, stream>>>(kfb, vfb, kvw, ksw);
    prefix_kv<<<dim3(4, BH), 256, 0, stream>>>(kvw, ksw, kvb, ksb);
    attn_out<<<BH * NC, 256, 0, stream>>>(qfb, kfb, vfb, kvb, ksb, attn);

    gemm256<1, D_, D_><<<dim3(D_ / 256, M_ / 256), 512, 0, stream>>>(
        attn, WoT, bout, out, nullptr, nullptr, nullptr);
}

// Round 7
// 249.167 us; speedup vs baseline: 1.4359x; 1.1336x over previous
//
#include <hip/hip_runtime.h>
#include <hip/hip_bf16.h>
#include <stdint.h>

#define B_ 4
#define L_ 4096
#define D_ 1024
#define H_ 16
#define E_ 64
#define M_ (B_*L_)       // 16384 rows
#define N1_ (3*D_)       // 3072
#define CHK 128
#define NC (L_/CHK)      // 32
#define BH (B_*H_)       // 64

#define EPS_FEAT 1.0001f
#define EPS_DEN 1e-6f

typedef __attribute__((ext_vector_type(4))) float f32x4;
typedef __attribute__((ext_vector_type(8))) short bf16x8;

__device__ __forceinline__ unsigned short f2bf(float x) {
    union { float f; unsigned int u; } v; v.f = x;
    unsigned int r = v.u + 0x7FFFu + ((v.u >> 16) & 1u);
    return (unsigned short)(r >> 16);
}

// async global->LDS, 16B per lane. LDS dest = wave-uniform base + lane*16.
__device__ __forceinline__ void gload_lds16(const unsigned short* g, unsigned short* l) {
    __builtin_amdgcn_global_load_lds(
        (const __attribute__((address_space(1))) unsigned int*)(const void*)g,
        (__attribute__((address_space(3))) unsigned int*)(void*)l,
        16, 0, 0);
}

// ---------------- prep kernels ----------------

__global__ __launch_bounds__(256) void cvt_x(const float* __restrict__ x,
                                             unsigned short* __restrict__ xb) {
    int i4 = blockIdx.x * 256 + threadIdx.x;      // float4 index
    float4 v = ((const float4*)x)[i4];
    unsigned int lo = (unsigned int)f2bf(v.x) | ((unsigned int)f2bf(v.y) << 16);
    unsigned int hi = (unsigned int)f2bf(v.z) | ((unsigned int)f2bf(v.w) << 16);
    ((uint2*)xb)[i4] = make_uint2(lo, hi);
}

// W (K,N) f32 -> WT (N,K) bf16
__global__ __launch_bounds__(256) void transp_w(const float* __restrict__ W,
                                                unsigned short* __restrict__ WT,
                                                int K, int N) {
    __shared__ float tile[32][33];
    int kb = blockIdx.y * 32, nb = blockIdx.x * 32;
    int tx = threadIdx.x & 31, ty = threadIdx.x >> 5;   // ty 0..7
#pragma unroll
    for (int j = 0; j < 4; ++j)
        tile[ty + 8*j][tx] = W[(size_t)(kb + ty + 8*j) * N + nb + tx];
    __syncthreads();
#pragma unroll
    for (int j = 0; j < 4; ++j) {
        int nl = ty + 8*j;
        WT[(size_t)(nb + nl) * K + kb + tx] = f2bf(tile[tx][nl]);
    }
}

// ---------------- 256x256 m201-style GEMM (A bf16 MxK, BT bf16 NxK) ----------------
// BK=64, 2-buffer dbuf (128KB), 4 phases/K-tile (16 MFMA each), 1 half-tile
// stage per phase, vmcnt(4) once per tile, row&7 XOR swizzle.
// Stage ledger: tile T: p1:T+1.A0, p2:T+1.A1 (other buffer, consumed at T-1.p3),
//               p3:T+2.B0, p4:T+2.B1 (this buffer, B fully read by p2).
// T+1's B halves were staged at T-1.p3/p4 -> T+1 complete by end of T.
// End-of-tile vmcnt(4): leaves only T+2.B0/B1 in flight, retires T+1.A*.

template<int MODE, int KDIM, int NDIM>
__global__ __launch_bounds__(512, 2) void gemm256(
    const unsigned short* __restrict__ A,
    const unsigned short* __restrict__ BT,
    const float* __restrict__ bias,
    float* __restrict__ outF,
    unsigned short* __restrict__ qf,
    unsigned short* __restrict__ kf,
    unsigned short* __restrict__ vf)
{
    __shared__ __align__(16) unsigned short smem[65536];   // 2 x (A 32KB | B 32KB)

    const int t = threadIdx.x, lane = t & 63, w = t >> 6;
    const int wr = w >> 2, wc = w & 3;                      // 2 x 4 wave grid

    // XCD-chunked bijective swizzle (nwg % 8 == 0 for both modes)
    const int nwgx = NDIM / 256;
    const int nwg = nwgx * (M_ / 256);
    const int bid0 = blockIdx.y * nwgx + blockIdx.x;
    const int swz = (bid0 & 7) * (nwg >> 3) + (bid0 >> 3);
    const int m0 = (swz / nwgx) * 256, n0 = (swz % nwgx) * 256;
    const int lr = lane & 15, lg = lane >> 4;

    // stage one half-tile (128 rows x 64 cols, 16KB): 2 x 16B chunks / thread.
    // inverse swizzle on global SOURCE; LDS dest linear.
    auto stage = [&](int T, int ab, int h) {
        unsigned short* base = smem + (T & 1) * 32768 + ab * 16384 + h * 8192;
        const unsigned short* src = ab ? BT : A;
        const int boff = (ab ? n0 : m0) + h * 128;
        const int kt = T * 64;
#pragma unroll
        for (int i = 0; i < 2; ++i) {
            int c = i * 512 + t;
            int rowl = c >> 3, s = c & 7;
            int col = ((s ^ (rowl & 7)) << 3);
            gload_lds16(src + (size_t)(boff + rowl) * KDIM + kt + col, &base[c * 8]);
        }
    };

    bf16x8 af[4][2], bq[4][2];
    f32x4 acc[8][4] = {};

    auto rdA = [&](const unsigned short* Ab, int m, int ks) {
        int row = wr * 128 + m * 16 + lr;
        int slot = (ks * 4 + lg) ^ (row & 7);
        return *(const bf16x8*)&Ab[row * 64 + slot * 8];
    };
    auto rdB = [&](const unsigned short* Bb, int n, int ks) {
        int row = wc * 64 + n * 16 + lr;
        int slot = (ks * 4 + lg) ^ (row & 7);
        return *(const bf16x8*)&Bb[row * 64 + slot * 8];
    };

#define PHASE_SYNC() \
    __builtin_amdgcn_s_barrier(); \
    asm volatile("s_waitcnt lgkmcnt(0)" ::: "memory"); \
    __builtin_amdgcn_sched_barrier(0); \
    __builtin_amdgcn_s_setprio(1);
#define PHASE_END() \
    __builtin_amdgcn_s_setprio(0); \
    __builtin_amdgcn_s_barrier();

    auto tile = [&](int T, bool s1, bool s2) {
        const unsigned short* Ab = smem + (T & 1) * 32768;
        const unsigned short* Bb = Ab + 16384;
        // ---- p1: (m0-3, n0-1) ----
#pragma unroll
        for (int m = 0; m < 4; ++m) { af[m][0] = rdA(Ab, m, 0); af[m][1] = rdA(Ab, m, 1); }
#pragma unroll
        for (int j = 0; j < 2; ++j) { bq[j][0] = rdB(Bb, j, 0); bq[j][1] = rdB(Bb, j, 1); }
        if (s1) stage(T + 1, 0, 0);
        PHASE_SYNC();
#pragma unroll
        for (int m = 0; m < 4; ++m)
#pragma unroll
            for (int j = 0; j < 2; ++j) {
                acc[m][j] = __builtin_amdgcn_mfma_f32_16x16x32_bf16(af[m][0], bq[j][0], acc[m][j], 0, 0, 0);
                acc[m][j] = __builtin_amdgcn_mfma_f32_16x16x32_bf16(af[m][1], bq[j][1], acc[m][j], 0, 0, 0);
            }
        PHASE_END();
        // ---- p2: (m0-3, n2-3) ----
#pragma unroll
        for (int j = 0; j < 2; ++j) { bq[2+j][0] = rdB(Bb, 2+j, 0); bq[2+j][1] = rdB(Bb, 2+j, 1); }
        if (s1) stage(T + 1, 0, 1);
        PHASE_SYNC();
#pragma unroll
        for (int m = 0; m < 4; ++m)
#pragma unroll
            for (int j = 0; j < 2; ++j) {
                acc[m][2+j] = __builtin_amdgcn_mfma_f32_16x16x32_bf16(af[m][0], bq[2+j][0], acc[m][2+j], 0, 0, 0);
                acc[m][2+j] = __builtin_amdgcn_mfma_f32_16x16x32_bf16(af[m][1], bq[2+j][1], acc[m][2+j], 0, 0, 0);
            }
        PHASE_END();
        // ---- p3: (m4-7, n0-1) ----
#pragma unroll
        for (int m = 0; m < 4; ++m) { af[m][0] = rdA(Ab, 4+m, 0); af[m][1] = rdA(Ab, 4+m, 1); }
        if (s2) stage(T + 2, 1, 0);
        PHASE_SYNC();
#pragma unroll
        for (int m = 0; m < 4; ++m)
#pragma unroll
            for (int j = 0; j < 2; ++j) {
                acc[4+m][j] = __builtin_amdgcn_mfma_f32_16x16x32_bf16(af[m][0], bq[j][0], acc[4+m][j], 0, 0, 0);
                acc[4+m][j] = __builtin_amdgcn_mfma_f32_16x16x32_bf16(af[m][1], bq[j][1], acc[4+m][j], 0, 0, 0);
            }
        PHASE_END();
        // ---- p4: (m4-7, n2-3) ----
        if (s2) stage(T + 2, 1, 1);
        PHASE_SYNC();
#pragma unroll
        for (int m = 0; m < 4; ++m)
#pragma unroll
            for (int j = 0; j < 2; ++j) {
                acc[4+m][2+j] = __builtin_amdgcn_mfma_f32_16x16x32_bf16(af[m][0], bq[2+j][0], acc[4+m][2+j], 0, 0, 0);
                acc[4+m][2+j] = __builtin_amdgcn_mfma_f32_16x16x32_bf16(af[m][1], bq[2+j][1], acc[4+m][2+j], 0, 0, 0);
            }
        __builtin_amdgcn_s_setprio(0);
        // end-of-tile vmcnt placed by caller, then barrier
    };

    constexpr int NT = KDIM / 64;                 // 16
    // prologue: T0 all 4 halves + T1.B0/B1 (T1.A staged during T0 p1/p2)
    stage(0, 0, 0); stage(0, 0, 1); stage(0, 1, 0); stage(0, 1, 1);
    stage(1, 1, 0); stage(1, 1, 1);
    asm volatile("s_waitcnt vmcnt(4)" ::: "memory");     // tile 0 landed
    __builtin_amdgcn_s_barrier();
    __builtin_amdgcn_sched_barrier(0);

    for (int T = 0; T < NT - 2; ++T) {
        tile(T, true, T + 2 < NT);
        asm volatile("s_waitcnt vmcnt(4)" ::: "memory"); // T+1 fully landed
        __builtin_amdgcn_s_barrier();
        __builtin_amdgcn_sched_barrier(0);
    }
    tile(NT - 2, true, false);                           // stages NT-1.A0/A1 only
    asm volatile("s_waitcnt vmcnt(0)" ::: "memory");     // NT-1 fully landed
    __builtin_amdgcn_s_barrier();
    __builtin_amdgcn_sched_barrier(0);
    tile(NT - 1, false, false);
    __syncthreads();                                     // LDS reuse below

    // ---------------- epilogues (LDS-routed, coalesced stores) ----------------
    if (MODE == 0) {
        unsigned short* cbf = smem;                      // [128][264] bf16 per pass
        const bool isQ = (n0 < D_), isK = (n0 >= D_ && n0 < 2*D_);
        const float scale = isQ ? 0.125f : 1.0f;
        unsigned short* buf = isQ ? qf : (isK ? kf : vf);
        const int b = m0 >> 12, l0 = m0 & 4095;
        const int h0 = (n0 & 1023) >> 6;
#pragma unroll
        for (int p = 0; p < 2; ++p) {
            if (wr == p) {
#pragma unroll
                for (int n = 0; n < 4; ++n) {
                    int cl = wc*64 + n*16 + lr;
                    float bv = bias[n0 + cl];
#pragma unroll
                    for (int m = 0; m < 8; ++m)
#pragma unroll
                        for (int q = 0; q < 4; ++q) {
                            int rl = m*16 + lg*4 + q;
                            float val = (acc[m][n][q] + bv) * scale;
                            float fv = (isQ || isK)
                                       ? ((val > 0.f ? val : __expf(val) - 1.f) + EPS_FEAT)
                                       : val;
                            cbf[rl * 264 + cl] = f2bf(fv);
                        }
                }
            }
            __syncthreads();
#pragma unroll
            for (int hh = 0; hh < 4; ++hh) {
                unsigned short* dst = buf + (((size_t)(b * H_ + h0 + hh)) * L_ + l0 + p*128) * E_;
#pragma unroll
                for (int i = 0; i < 2; ++i) {
                    int c = i*512 + t, row = c >> 3, ch = c & 7;
                    uint4 v = *(const uint4*)&cbf[row * 264 + hh*64 + ch*8];
                    *(uint4*)&dst[row * 64 + ch*8] = v;
                }
            }
            __syncthreads();
        }
    } else {
        float* cfl = (float*)smem;                       // [64][260] f32 per pass
#pragma unroll
        for (int p = 0; p < 4; ++p) {
            if (wr == (p >> 1)) {
                int mbase = (p & 1) * 4;
#pragma unroll
                for (int n = 0; n < 4; ++n) {
                    int cl = wc*64 + n*16 + lr;
                    float bv = bias[n0 + cl];
#pragma unroll
                    for (int mm = 0; mm < 4; ++mm)
#pragma unroll
                        for (int q = 0; q < 4; ++q) {
                            int rl = mm*16 + lg*4 + q;
                            cfl[rl * 260 + cl] = acc[mbase + mm][n][q] + bv;
                        }
                }
            }
            __syncthreads();
#pragma unroll
            for (int i = 0; i < 8; ++i) {
                int c = i*512 + t, row = c >> 6, ch = c & 63;
                float4 v = *(const float4*)&cfl[row * 260 + ch*4];
                *(float4*)&outF[(size_t)(m0 + p*64 + row) * NDIM + n0 + ch*4] = v;
            }
            __syncthreads();
        }
    }
#undef PHASE_SYNC
#undef PHASE_END
}

// ---------------- chunk KV (TRANSPOSED state): KVT_c[f][e] = sum_l V[l][f] K[l][e] ----------------
// ksum via Vt ones-row (row 64) as A-operand on wave 0.

__global__ __launch_bounds__(256) void chunk_kv(
    const unsigned short* __restrict__ kf, const unsigned short* __restrict__ vf,
    float* __restrict__ kvout, float* __restrict__ ksout)
{
    constexpr int LDK = 136;                 // 128 + 8 pad
    __shared__ unsigned short Kt[64 * LDK];  // K^T : [e][l]
    __shared__ unsigned short Vt[80 * LDK];  // V^T : [f][l], row 64 = ones (ksum trick)

    int t = threadIdx.x, lane = t & 63, w = t >> 6;
    int bid = blockIdx.x;                    // bh*NC + c
    const unsigned short* kp = kf + (size_t)bid * CHK * E_;
    const unsigned short* vp = vf + (size_t)bid * CHK * E_;

#pragma unroll
    for (int it = 0; it < 4; ++it) {
        int s = it * 256 + t;                // 0..1023  (16B granules of 128x64)
        int rl = s >> 3, e0 = (s & 7) << 3;
        uint4 kv8 = *(const uint4*)(kp + s * 8);
        uint4 vv8 = *(const uint4*)(vp + s * 8);
        unsigned int kw[4] = {kv8.x, kv8.y, kv8.z, kv8.w};
        unsigned int vw[4] = {vv8.x, vv8.y, vv8.z, vv8.w};
#pragma unroll
        for (int jw = 0; jw < 4; ++jw) {
            Kt[(e0 + 2*jw    ) * LDK + rl] = (unsigned short)(kw[jw] & 0xFFFF);
            Kt[(e0 + 2*jw + 1) * LDK + rl] = (unsigned short)(kw[jw] >> 16);
            Vt[(e0 + 2*jw    ) * LDK + rl] = (unsigned short)(vw[jw] & 0xFFFF);
            Vt[(e0 + 2*jw + 1) * LDK + rl] = (unsigned short)(vw[jw] >> 16);
        }
    }
    if (t < 128) Vt[64 * LDK + t] = 0x3F80;  // bf16 1.0
    for (int i = t; i < 15 * LDK; i += 256) Vt[65 * LDK + i] = 0;
    __syncthreads();

    int lr = lane & 15, lg = lane >> 4;
    f32x4 acc[4] = {};
    f32x4 accE[4] = {};
#pragma unroll
    for (int ks = 0; ks < 4; ++ks) {
        bf16x8 a = *(const bf16x8*)&Vt[(w*16 + lr) * LDK + ks*32 + lg*8];
#pragma unroll
        for (int n = 0; n < 4; ++n) {
            bf16x8 b = *(const bf16x8*)&Kt[(n*16 + lr) * LDK + ks*32 + lg*8];
            acc[n] = __builtin_amdgcn_mfma_f32_16x16x32_bf16(a, b, acc[n], 0, 0, 0);
        }
    }
    if (w == 0) {
#pragma unroll
        for (int ks = 0; ks < 4; ++ks) {
            bf16x8 a = *(const bf16x8*)&Vt[(64 + lr) * LDK + ks*32 + lg*8];
#pragma unroll
            for (int n = 0; n < 4; ++n) {
                bf16x8 b = *(const bf16x8*)&Kt[(n*16 + lr) * LDK + ks*32 + lg*8];
                accE[n] = __builtin_amdgcn_mfma_f32_16x16x32_bf16(a, b, accE[n], 0, 0, 0);
            }
        }
    }
    float* kvo = kvout + (size_t)bid * E_ * E_;   // [f][e]
#pragma unroll
    for (int n = 0; n < 4; ++n)
#pragma unroll
        for (int q = 0; q < 4; ++q) {
            int f = w*16 + lg*4 + q, e = n*16 + lr;
            kvo[f * 64 + e] = acc[n][q];
        }
    if (w == 0 && lg == 0) {
#pragma unroll
        for (int n = 0; n < 4; ++n)
            ksout[(size_t)bid * 64 + n*16 + lr] = accE[n][0];   // row 64 = ksum
    }
}

// ---------------- exclusive prefix over chunks (per bh), bf16 output ----------------

__global__ __launch_bounds__(256) void prefix_kv(
    const float* __restrict__ kv, const float* __restrict__ ks,
    unsigned short* __restrict__ kvb, unsigned short* __restrict__ ksb)
{
    int bh = blockIdx.y, part = blockIdx.x, t = threadIdx.x;
    int idx = part * 256 + t;
    float st = 0.f;
    for (int c = 0; c < NC; ++c) {
        float tmp = kv[((size_t)bh * NC + c) * 4096 + idx];
        kvb[((size_t)bh * NC + c) * 4096 + idx] = f2bf(st);
        st += tmp;
    }
    if (part == 0 && t < 64) {
        float s0 = 0.f;
        for (int c = 0; c < NC; ++c) {
            float tmp = ks[((size_t)bh * NC + c) * 64 + t];
            ksb[((size_t)bh * NC + c) * 64 + t] = f2bf(s0);
            s0 += tmp;
        }
    }
}

// ---------------- attention output per (bh, chunk) ----------------
// LDS 69KB -> 2 blocks/CU. Q frags in regs (global), KV-state frags from
// global ([f][e] bf16), den rows (ones / ksum) built in registers.

__global__ __launch_bounds__(256, 2) void attn_out(
    const unsigned short* __restrict__ qf, const unsigned short* __restrict__ kf,
    const unsigned short* __restrict__ vf, const unsigned short* __restrict__ kvb,
    const unsigned short* __restrict__ ksb, unsigned short* __restrict__ attn)
{
    constexpr int LK = 72;    // K stride (64+8)
    constexpr int LV = 136;   // Vt & S stride (128+8)
    __shared__ unsigned short Ks[128 * LK];   // 18.0 KB
    __shared__ unsigned short Vt[64 * LV];    // 17.0 KB
    __shared__ unsigned short Ss[128 * LV];   // 34.0 KB

    int t = threadIdx.x, lane = t & 63, w = t >> 6;
    int bid = blockIdx.x;
    int bh = bid >> 5, c = bid & 31;
    const unsigned short* qp = qf + (size_t)bid * CHK * E_;
    const unsigned short* kp = kf + (size_t)bid * CHK * E_;
    const unsigned short* vp = vf + (size_t)bid * CHK * E_;
    const unsigned short* kvp = kvb + (size_t)bid * 4096;   // [f][e]

    int lr = lane & 15, lg = lane >> 4;

    // Q frags: rows w*32 + m*16 + lr, cols ks*32 + lg*8 (global, coalesced 64B)
    bf16x8 aq[2][2];
#pragma unroll
    for (int m = 0; m < 2; ++m)
#pragma unroll
        for (int ks = 0; ks < 2; ++ks)
            aq[m][ks] = *(const bf16x8*)(qp + (w*32 + m*16 + lr) * 64 + ks*32 + lg*8);

#pragma unroll
    for (int it = 0; it < 4; ++it) {
        int s = it * 256 + t;
        int r = s >> 3, e0 = (s & 7) << 3;
        uint4 kv = *(const uint4*)(kp + s * 8);
        uint4 vv = *(const uint4*)(vp + s * 8);
        *(uint4*)&Ks[r * LK + e0] = kv;
        unsigned int vw[4] = {vv.x, vv.y, vv.z, vv.w};
#pragma unroll
        for (int jw = 0; jw < 4; ++jw) {
            Vt[(e0 + 2*jw    ) * LV + r] = (unsigned short)(vw[jw] & 0xFFFF);
            Vt[(e0 + 2*jw + 1) * LV + r] = (unsigned short)(vw[jw] >> 16);
        }
    }
    // den B-rows in regs: row 64+lr -> only lr==0 lanes hold data
    bf16x8 zfrag = {0,0,0,0,0,0,0,0};
    bf16x8 bone = zfrag, bks[2] = {zfrag, zfrag};
    if (lr == 0) {
#pragma unroll
        for (int j = 0; j < 8; ++j) bone[j] = (short)0x3F80;
        bks[0] = *(const bf16x8*)&ksb[(size_t)bid * 64 + lg*8];
        bks[1] = *(const bf16x8*)&ksb[(size_t)bid * 64 + 32 + lg*8];
    }
    __syncthreads();

    // S-phase: wave w owns rows [w*32, w*32+32)
#pragma unroll
    for (int m = 0; m < 2; ++m) {
        int rbase = w * 32 + m * 16;
        int jmax = 2 * w + m;
        for (int jb = 0; jb < 8; ++jb) {
            if (jb <= jmax) {
                f32x4 sacc = {};
                bf16x8 b0 = *(const bf16x8*)&Ks[(jb*16 + lr) * LK + lg*8];
                bf16x8 b1 = *(const bf16x8*)&Ks[(jb*16 + lr) * LK + 32 + lg*8];
                sacc = __builtin_amdgcn_mfma_f32_16x16x32_bf16(aq[m][0], b0, sacc, 0, 0, 0);
                sacc = __builtin_amdgcn_mfma_f32_16x16x32_bf16(aq[m][1], b1, sacc, 0, 0, 0);
#pragma unroll
                for (int q = 0; q < 4; ++q) {
                    int r = rbase + lg*4 + q;
                    int j = jb*16 + lr;
                    Ss[r * LV + j] = (j <= r) ? f2bf(sacc[q]) : (unsigned short)0;
                }
            } else {
#pragma unroll
                for (int q = 0; q < 4; ++q) {
                    int r = rbase + lg*4 + q;
                    Ss[r * LV + jb*16 + lr] = 0;
                }
            }
        }
    }
    // no barrier needed: each wave reads only its own S rows below

    f32x4 oacc[2][5] = {};
#pragma unroll
    for (int m = 0; m < 2; ++m) {
        int rbase = w * 32 + m * 16;
        // inter-chunk: Q @ KV_state (K-dim 64); B frags from global [f][e]
#pragma unroll
        for (int ks = 0; ks < 2; ++ks) {
            bf16x8 a = aq[m][ks];
#pragma unroll
            for (int n = 0; n < 4; ++n) {
                bf16x8 b = *(const bf16x8*)&kvp[(n*16 + lr) * 64 + ks*32 + lg*8];
                oacc[m][n] = __builtin_amdgcn_mfma_f32_16x16x32_bf16(a, b, oacc[m][n], 0, 0, 0);
            }
            oacc[m][4] = __builtin_amdgcn_mfma_f32_16x16x32_bf16(a, bks[ks], oacc[m][4], 0, 0, 0);
        }
        // intra-chunk: S @ V  (only k-blocks <= w are nonzero)
        for (int ks = 0; ks <= w; ++ks) {
            bf16x8 a = *(const bf16x8*)&Ss[(rbase + lr) * LV + ks*32 + lg*8];
#pragma unroll
            for (int n = 0; n < 4; ++n) {
                bf16x8 b = *(const bf16x8*)&Vt[(n*16 + lr) * LV + ks*32 + lg*8];
                oacc[m][n] = __builtin_amdgcn_mfma_f32_16x16x32_bf16(a, b, oacc[m][n], 0, 0, 0);
            }
            oacc[m][4] = __builtin_amdgcn_mfma_f32_16x16x32_bf16(a, bone, oacc[m][4], 0, 0, 0);
        }
    }

    // den broadcast (col 64 lives in lanes with lr==0) + normalize + store
    int b_idx = bh >> 4, h_idx = bh & 15;
#pragma unroll
    for (int m = 0; m < 2; ++m) {
        int rbase = w * 32 + m * 16;
        float den[4];
#pragma unroll
        for (int q = 0; q < 4; ++q)
            den[q] = __shfl(oacc[m][4][q], lane & 48, 64) + EPS_DEN;
#pragma unroll
        for (int n = 0; n < 4; ++n) {
#pragma unroll
            for (int q = 0; q < 4; ++q) {
                int r = rbase + lg*4 + q;
                int lpos = c * CHK + r;
                int col = n*16 + lr;
                size_t dst = ((size_t)b_idx * L_ + lpos) * D_ + h_idx * 64 + col;
                attn[dst] = f2bf(oacc[m][n][q] / den[q]);
            }
        }
    }
}

// ---------------- launcher ----------------

extern "C" void kernel_launch(void* const* d_in, const int* in_sizes, int n_in,
                              void* d_out, int out_size, void* d_ws, size_t ws_size,
                              hipStream_t stream)
{
    const float* x    = (const float*)d_in[0];
    const float* Wqkv = (const float*)d_in[1];
    const float* bqkv = (const float*)d_in[2];
    const float* Wout = (const float*)d_in[3];
    const float* bout = (const float*)d_in[4];
    float* out = (float*)d_out;

    char* ws = (char*)d_ws;
    size_t off = 0;
    auto alloc = [&](size_t bytes) { void* p = ws + off; off += (bytes + 255) & ~(size_t)255; return p; };
    unsigned short* xb  = (unsigned short*)alloc((size_t)M_ * D_ * 2);
    unsigned short* WqT = (unsigned short*)alloc((size_t)N1_ * D_ * 2);
    unsigned short* WoT = (unsigned short*)alloc((size_t)D_ * D_ * 2);
    unsigned short* qfb = (unsigned short*)alloc((size_t)M_ * D_ * 2);
    unsigned short* kfb = (unsigned short*)alloc((size_t)M_ * D_ * 2);
    unsigned short* vfb = (unsigned short*)alloc((size_t)M_ * D_ * 2);
    float* kvw = (float*)alloc((size_t)BH * NC * E_ * E_ * 4);
    float* ksw = (float*)alloc((size_t)BH * NC * E_ * 4);
    unsigned short* kvb = (unsigned short*)alloc((size_t)BH * NC * E_ * E_ * 2);
    unsigned short* ksb = (unsigned short*)alloc((size_t)BH * NC * E_ * 2);
    unsigned short* attn = xb;   // alias: x_bf16 is dead after gemm<0>

    cvt_x<<<(M_ * D_ / 4) / 256, 256, 0, stream>>>(x, xb);
    transp_w<<<dim3(N1_ / 32, D_ / 32), 256, 0, stream>>>(Wqkv, WqT, D_, N1_);
    transp_w<<<dim3(D_ / 32, D_ / 32), 256, 0, stream>>>(Wout, WoT, D_, D_);

    gemm256<0, D_, N1_><<<dim3(N1_ / 256, M_ / 256), 512, 0, stream>>>(
        xb, WqT, bqkv, nullptr, qfb, kfb, vfb);

    chunk_kv<<<BH * NC, 256, 0, stream>>>(kfb, vfb, kvw, ksw);
    prefix_kv<<<dim3(16, BH), 256, 0, stream>>>(kvw, ksw, kvb, ksb);
    attn_out<<<BH * NC, 256, 0, stream>>>(qfb, kfb, vfb, kvb, ksb, attn);

    gemm256<1, D_, D_><<<dim3(D_ / 256, M_ / 256), 512, 0, stream>>>(
        attn, WoT, bout, out, nullptr, nullptr, nullptr);
}

// Round 8
// 242.078 us; speedup vs baseline: 1.4780x; 1.0293x over previous
//
#include <hip/hip_runtime.h>
#include <hip/hip_bf16.h>
#include <stdint.h>

#define B_ 4
#define L_ 4096
#define D_ 1024
#define H_ 16
#define E_ 64
#define M_ (B_*L_)       // 16384 rows
#define N1_ (3*D_)       // 3072
#define CHK 128
#define NC (L_/CHK)      // 32
#define BH (B_*H_)       // 64

#define EPS_FEAT 1.0001f
#define EPS_DEN 1e-6f

typedef __attribute__((ext_vector_type(4))) float f32x4;
typedef __attribute__((ext_vector_type(8))) short bf16x8;

__device__ __forceinline__ unsigned short f2bf(float x) {
    union { float f; unsigned int u; } v; v.f = x;
    unsigned int r = v.u + 0x7FFFu + ((v.u >> 16) & 1u);
    return (unsigned short)(r >> 16);
}

// async global->LDS, 16B per lane. LDS dest = wave-uniform base + lane*16.
__device__ __forceinline__ void gload_lds16(const unsigned short* g, unsigned short* l) {
    __builtin_amdgcn_global_load_lds(
        (const __attribute__((address_space(1))) unsigned int*)(const void*)g,
        (__attribute__((address_space(3))) unsigned int*)(void*)l,
        16, 0, 0);
}

// ---------------- prep kernels ----------------

__global__ __launch_bounds__(256) void cvt_x(const float* __restrict__ x,
                                             unsigned short* __restrict__ xb) {
    int i4 = blockIdx.x * 256 + threadIdx.x;      // float4 index
    float4 v = ((const float4*)x)[i4];
    unsigned int lo = (unsigned int)f2bf(v.x) | ((unsigned int)f2bf(v.y) << 16);
    unsigned int hi = (unsigned int)f2bf(v.z) | ((unsigned int)f2bf(v.w) << 16);
    ((uint2*)xb)[i4] = make_uint2(lo, hi);
}

// both weight transposes in one launch: z=0 -> Wqkv (N=3072), z=1 -> Wout (N=1024)
__global__ __launch_bounds__(256) void transp_w2(const float* __restrict__ W0,
                                                 const float* __restrict__ W1,
                                                 unsigned short* __restrict__ T0,
                                                 unsigned short* __restrict__ T1) {
    int z = blockIdx.z;
    if (z == 1 && blockIdx.x >= (D_ / 32)) return;
    const float* W = z ? W1 : W0;
    unsigned short* WT = z ? T1 : T0;
    int N = z ? D_ : N1_;
    __shared__ float tile[32][33];
    int kb = blockIdx.y * 32, nb = blockIdx.x * 32;
    int tx = threadIdx.x & 31, ty = threadIdx.x >> 5;   // ty 0..7
#pragma unroll
    for (int j = 0; j < 4; ++j)
        tile[ty + 8*j][tx] = W[(size_t)(kb + ty + 8*j) * N + nb + tx];
    __syncthreads();
#pragma unroll
    for (int j = 0; j < 4; ++j) {
        int nl = ty + 8*j;
        WT[(size_t)(nb + nl) * D_ + kb + tx] = f2bf(tile[tx][nl]);
    }
}

// ---------------- 256x256 pipelined GEMM (A bf16 MxK, BT bf16 NxK) ----------------
// BK=64, 2-buffer dbuf (128KB), 4 phases/K-tile, ONE barrier per phase
// (pre-MFMA), vmcnt(4) once per tile, row&7 XOR swizzle.
// Stage slots (WAR-safe under 1-barrier phases):
//   p1: T+1.A0, p2: T+1.A1   (other buffer; last read of that region was
//       T-1.p3, boundary barrier + p4 in between -> >=2 barriers margin)
//   p4: T+2.B0 AND T+2.B1    (current buffer; B region last ds_read at p2,
//       p4 issue is after p3-pre barrier -> every wave's p2 lgkmcnt(0) done)
// Per-wave issue order chronological -> end-of-tile vmcnt(4) retires
// [T+1.B (from T-1.p4), T+1.A], leaves T+2.B in flight. Boundary barrier
// makes per-wave vmcnt collective.

template<int MODE, int KDIM, int NDIM>
__global__ __launch_bounds__(512, 2) void gemm256(
    const unsigned short* __restrict__ A,
    const unsigned short* __restrict__ BT,
    const float* __restrict__ bias,
    float* __restrict__ outF,
    unsigned short* __restrict__ qf,
    unsigned short* __restrict__ kf,
    unsigned short* __restrict__ vf)
{
    __shared__ __align__(16) unsigned short smem[65536];   // 2 x (A 32KB | B 32KB)

    const int t = threadIdx.x, lane = t & 63, w = t >> 6;
    const int wr = w >> 2, wc = w & 3;                      // 2 x 4 wave grid

    // XCD-chunked bijective swizzle (nwg % 8 == 0 for both modes)
    const int nwgx = NDIM / 256;
    const int nwg = nwgx * (M_ / 256);
    const int bid0 = blockIdx.y * nwgx + blockIdx.x;
    const int swz = (bid0 & 7) * (nwg >> 3) + (bid0 >> 3);
    const int m0 = (swz / nwgx) * 256, n0 = (swz % nwgx) * 256;
    const int lr = lane & 15, lg = lane >> 4;

    // stage one half-tile (128 rows x 64 cols, 16KB): 2 x 16B chunks / thread.
    // inverse swizzle on global SOURCE; LDS dest linear.
    auto stage = [&](int T, int ab, int h) {
        unsigned short* base = smem + (T & 1) * 32768 + ab * 16384 + h * 8192;
        const unsigned short* src = ab ? BT : A;
        const int boff = (ab ? n0 : m0) + h * 128;
        const int kt = T * 64;
#pragma unroll
        for (int i = 0; i < 2; ++i) {
            int c = i * 512 + t;
            int rowl = c >> 3, s = c & 7;
            int col = ((s ^ (rowl & 7)) << 3);
            gload_lds16(src + (size_t)(boff + rowl) * KDIM + kt + col, &base[c * 8]);
        }
    };

    bf16x8 af[4][2], bq[4][2];
    f32x4 acc[8][4] = {};

    auto rdA = [&](const unsigned short* Ab, int m, int ks) {
        int row = wr * 128 + m * 16 + lr;
        int slot = (ks * 4 + lg) ^ (row & 7);
        return *(const bf16x8*)&Ab[row * 64 + slot * 8];
    };
    auto rdB = [&](const unsigned short* Bb, int n, int ks) {
        int row = wc * 64 + n * 16 + lr;
        int slot = (ks * 4 + lg) ^ (row & 7);
        return *(const bf16x8*)&Bb[row * 64 + slot * 8];
    };

#define PHASE_PRE() \
    __builtin_amdgcn_s_barrier(); \
    asm volatile("s_waitcnt lgkmcnt(0)" ::: "memory"); \
    __builtin_amdgcn_sched_barrier(0); \
    __builtin_amdgcn_s_setprio(1);
#define PHASE_POST() \
    __builtin_amdgcn_s_setprio(0);

    auto tile = [&](int T, bool s1, bool s2) {
        const unsigned short* Ab = smem + (T & 1) * 32768;
        const unsigned short* Bb = Ab + 16384;
        // ---- p1: (m0-3, n0-1); stage T+1.A0 ----
#pragma unroll
        for (int m = 0; m < 4; ++m) { af[m][0] = rdA(Ab, m, 0); af[m][1] = rdA(Ab, m, 1); }
#pragma unroll
        for (int j = 0; j < 2; ++j) { bq[j][0] = rdB(Bb, j, 0); bq[j][1] = rdB(Bb, j, 1); }
        if (s1) stage(T + 1, 0, 0);
        PHASE_PRE();
#pragma unroll
        for (int m = 0; m < 4; ++m)
#pragma unroll
            for (int j = 0; j < 2; ++j) {
                acc[m][j] = __builtin_amdgcn_mfma_f32_16x16x32_bf16(af[m][0], bq[j][0], acc[m][j], 0, 0, 0);
                acc[m][j] = __builtin_amdgcn_mfma_f32_16x16x32_bf16(af[m][1], bq[j][1], acc[m][j], 0, 0, 0);
            }
        PHASE_POST();
        // ---- p2: (m0-3, n2-3); stage T+1.A1 ----
#pragma unroll
        for (int j = 0; j < 2; ++j) { bq[2+j][0] = rdB(Bb, 2+j, 0); bq[2+j][1] = rdB(Bb, 2+j, 1); }
        if (s1) stage(T + 1, 0, 1);
        PHASE_PRE();
#pragma unroll
        for (int m = 0; m < 4; ++m)
#pragma unroll
            for (int j = 0; j < 2; ++j) {
                acc[m][2+j] = __builtin_amdgcn_mfma_f32_16x16x32_bf16(af[m][0], bq[2+j][0], acc[m][2+j], 0, 0, 0);
                acc[m][2+j] = __builtin_amdgcn_mfma_f32_16x16x32_bf16(af[m][1], bq[2+j][1], acc[m][2+j], 0, 0, 0);
            }
        PHASE_POST();
        // ---- p3: (m4-7, n0-1); no stage ----
#pragma unroll
        for (int m = 0; m < 4; ++m) { af[m][0] = rdA(Ab, 4+m, 0); af[m][1] = rdA(Ab, 4+m, 1); }
        PHASE_PRE();
#pragma unroll
        for (int m = 0; m < 4; ++m)
#pragma unroll
            for (int j = 0; j < 2; ++j) {
                acc[4+m][j] = __builtin_amdgcn_mfma_f32_16x16x32_bf16(af[m][0], bq[j][0], acc[4+m][j], 0, 0, 0);
                acc[4+m][j] = __builtin_amdgcn_mfma_f32_16x16x32_bf16(af[m][1], bq[j][1], acc[4+m][j], 0, 0, 0);
            }
        PHASE_POST();
        // ---- p4: (m4-7, n2-3); stage T+2.B0 + T+2.B1 ----
        if (s2) { stage(T + 2, 1, 0); stage(T + 2, 1, 1); }
        PHASE_PRE();
#pragma unroll
        for (int m = 0; m < 4; ++m)
#pragma unroll
            for (int j = 0; j < 2; ++j) {
                acc[4+m][2+j] = __builtin_amdgcn_mfma_f32_16x16x32_bf16(af[m][0], bq[2+j][0], acc[4+m][2+j], 0, 0, 0);
                acc[4+m][2+j] = __builtin_amdgcn_mfma_f32_16x16x32_bf16(af[m][1], bq[2+j][1], acc[4+m][2+j], 0, 0, 0);
            }
        PHASE_POST();
        // end-of-tile vmcnt + barrier placed by caller
    };

    constexpr int NT = KDIM / 64;                 // 16
    // prologue: T0 all 4 halves + T1.B0/B1 (T1.A staged during T0 p1/p2)
    stage(0, 0, 0); stage(0, 0, 1); stage(0, 1, 0); stage(0, 1, 1);
    stage(1, 1, 0); stage(1, 1, 1);
    asm volatile("s_waitcnt vmcnt(4)" ::: "memory");     // tile 0 landed
    __builtin_amdgcn_s_barrier();
    __builtin_amdgcn_sched_barrier(0);

    for (int T = 0; T < NT - 2; ++T) {
        tile(T, true, true);
        asm volatile("s_waitcnt vmcnt(4)" ::: "memory"); // T+1 fully landed
        __builtin_amdgcn_s_barrier();
        __builtin_amdgcn_sched_barrier(0);
    }
    tile(NT - 2, true, false);                           // stages NT-1.A0/A1 only
    asm volatile("s_waitcnt vmcnt(0)" ::: "memory");     // NT-1 fully landed
    __builtin_amdgcn_s_barrier();
    __builtin_amdgcn_sched_barrier(0);
    tile(NT - 1, false, false);
    __syncthreads();                                     // LDS reuse below

    // ---------------- epilogues (LDS-routed, coalesced stores) ----------------
    if (MODE == 0) {
        unsigned short* cbf = smem;                      // [128][264] bf16 per pass
        const bool isQ = (n0 < D_), isK = (n0 >= D_ && n0 < 2*D_);
        const float scale = isQ ? 0.125f : 1.0f;
        unsigned short* buf = isQ ? qf : (isK ? kf : vf);
        const int b = m0 >> 12, l0 = m0 & 4095;
        const int h0 = (n0 & 1023) >> 6;
#pragma unroll
        for (int p = 0; p < 2; ++p) {
            if (wr == p) {
#pragma unroll
                for (int n = 0; n < 4; ++n) {
                    int cl = wc*64 + n*16 + lr;
                    float bv = bias[n0 + cl];
#pragma unroll
                    for (int m = 0; m < 8; ++m)
#pragma unroll
                        for (int q = 0; q < 4; ++q) {
                            int rl = m*16 + lg*4 + q;
                            float val = (acc[m][n][q] + bv) * scale;
                            float fv = (isQ || isK)
                                       ? ((val > 0.f ? val : __expf(val) - 1.f) + EPS_FEAT)
                                       : val;
                            cbf[rl * 264 + cl] = f2bf(fv);
                        }
                }
            }
            __syncthreads();
#pragma unroll
            for (int hh = 0; hh < 4; ++hh) {
                unsigned short* dst = buf + (((size_t)(b * H_ + h0 + hh)) * L_ + l0 + p*128) * E_;
#pragma unroll
                for (int i = 0; i < 2; ++i) {
                    int c = i*512 + t, row = c >> 3, ch = c & 7;
                    uint4 v = *(const uint4*)&cbf[row * 264 + hh*64 + ch*8];
                    *(uint4*)&dst[row * 64 + ch*8] = v;
                }
            }
            __syncthreads();
        }
    } else {
        float* cfl = (float*)smem;                       // [64][260] f32 per pass
#pragma unroll
        for (int p = 0; p < 4; ++p) {
            if (wr == (p >> 1)) {
                int mbase = (p & 1) * 4;
#pragma unroll
                for (int n = 0; n < 4; ++n) {
                    int cl = wc*64 + n*16 + lr;
                    float bv = bias[n0 + cl];
#pragma unroll
                    for (int mm = 0; mm < 4; ++mm)
#pragma unroll
                        for (int q = 0; q < 4; ++q) {
                            int rl = mm*16 + lg*4 + q;
                            cfl[rl * 260 + cl] = acc[mbase + mm][n][q] + bv;
                        }
                }
            }
            __syncthreads();
#pragma unroll
            for (int i = 0; i < 8; ++i) {
                int c = i*512 + t, row = c >> 6, ch = c & 63;
                float4 v = *(const float4*)&cfl[row * 260 + ch*4];
                *(float4*)&outF[(size_t)(m0 + p*64 + row) * NDIM + n0 + ch*4] = v;
            }
            __syncthreads();
        }
    }
#undef PHASE_PRE
#undef PHASE_POST
}

// ---------------- chunk KV (TRANSPOSED state): KVT_c[f][e] = sum_l V[l][f] K[l][e] ----------------
// ksum via Vt ones-row (row 64) as A-operand on wave 0.

__global__ __launch_bounds__(256) void chunk_kv(
    const unsigned short* __restrict__ kf, const unsigned short* __restrict__ vf,
    float* __restrict__ kvout, float* __restrict__ ksout)
{
    constexpr int LDK = 136;                 // 128 + 8 pad
    __shared__ unsigned short Kt[64 * LDK];  // K^T : [e][l]
    __shared__ unsigned short Vt[80 * LDK];  // V^T : [f][l], row 64 = ones (ksum trick)

    int t = threadIdx.x, lane = t & 63, w = t >> 6;
    int bid = blockIdx.x;                    // bh*NC + c
    const unsigned short* kp = kf + (size_t)bid * CHK * E_;
    const unsigned short* vp = vf + (size_t)bid * CHK * E_;

#pragma unroll
    for (int it = 0; it < 4; ++it) {
        int s = it * 256 + t;                // 0..1023  (16B granules of 128x64)
        int rl = s >> 3, e0 = (s & 7) << 3;
        uint4 kv8 = *(const uint4*)(kp + s * 8);
        uint4 vv8 = *(const uint4*)(vp + s * 8);
        unsigned int kw[4] = {kv8.x, kv8.y, kv8.z, kv8.w};
        unsigned int vw[4] = {vv8.x, vv8.y, vv8.z, vv8.w};
#pragma unroll
        for (int jw = 0; jw < 4; ++jw) {
            Kt[(e0 + 2*jw    ) * LDK + rl] = (unsigned short)(kw[jw] & 0xFFFF);
            Kt[(e0 + 2*jw + 1) * LDK + rl] = (unsigned short)(kw[jw] >> 16);
            Vt[(e0 + 2*jw    ) * LDK + rl] = (unsigned short)(vw[jw] & 0xFFFF);
            Vt[(e0 + 2*jw + 1) * LDK + rl] = (unsigned short)(vw[jw] >> 16);
        }
    }
    if (t < 128) Vt[64 * LDK + t] = 0x3F80;  // bf16 1.0
    for (int i = t; i < 15 * LDK; i += 256) Vt[65 * LDK + i] = 0;
    __syncthreads();

    int lr = lane & 15, lg = lane >> 4;
    f32x4 acc[4] = {};
    f32x4 accE[4] = {};
#pragma unroll
    for (int ks = 0; ks < 4; ++ks) {
        bf16x8 a = *(const bf16x8*)&Vt[(w*16 + lr) * LDK + ks*32 + lg*8];
#pragma unroll
        for (int n = 0; n < 4; ++n) {
            bf16x8 b = *(const bf16x8*)&Kt[(n*16 + lr) * LDK + ks*32 + lg*8];
            acc[n] = __builtin_amdgcn_mfma_f32_16x16x32_bf16(a, b, acc[n], 0, 0, 0);
        }
    }
    if (w == 0) {
#pragma unroll
        for (int ks = 0; ks < 4; ++ks) {
            bf16x8 a = *(const bf16x8*)&Vt[(64 + lr) * LDK + ks*32 + lg*8];
#pragma unroll
            for (int n = 0; n < 4; ++n) {
                bf16x8 b = *(const bf16x8*)&Kt[(n*16 + lr) * LDK + ks*32 + lg*8];
                accE[n] = __builtin_amdgcn_mfma_f32_16x16x32_bf16(a, b, accE[n], 0, 0, 0);
            }
        }
    }
    float* kvo = kvout + (size_t)bid * E_ * E_;   // [f][e]
#pragma unroll
    for (int n = 0; n < 4; ++n)
#pragma unroll
        for (int q = 0; q < 4; ++q) {
            int f = w*16 + lg*4 + q, e = n*16 + lr;
            kvo[f * 64 + e] = acc[n][q];
        }
    if (w == 0 && lg == 0) {
#pragma unroll
        for (int n = 0; n < 4; ++n)
            ksout[(size_t)bid * 64 + n*16 + lr] = accE[n][0];   // row 64 = ksum
    }
}

// ---------------- exclusive prefix over chunks (per bh), bf16 output ----------------

__global__ __launch_bounds__(256) void prefix_kv(
    const float* __restrict__ kv, const float* __restrict__ ks,
    unsigned short* __restrict__ kvb, unsigned short* __restrict__ ksb)
{
    int bh = blockIdx.y, part = blockIdx.x, t = threadIdx.x;
    int idx = part * 256 + t;
    float st = 0.f;
    for (int c = 0; c < NC; ++c) {
        float tmp = kv[((size_t)bh * NC + c) * 4096 + idx];
        kvb[((size_t)bh * NC + c) * 4096 + idx] = f2bf(st);
        st += tmp;
    }
    if (part == 0 && t < 64) {
        float s0 = 0.f;
        for (int c = 0; c < NC; ++c) {
            float tmp = ks[((size_t)bh * NC + c) * 64 + t];
            ksb[((size_t)bh * NC + c) * 64 + t] = f2bf(s0);
            s0 += tmp;
        }
    }
}

// ---------------- attention output per (bh, chunk) ----------------
// LDS 69KB -> 2 blocks/CU. Wave w owns row-blocks {w, 7-w} (balanced causal
// cost: S = 9 block-pairs/wave, PV-intra = 5 ks-iters/wave, all waves equal).

__global__ __launch_bounds__(256, 2) void attn_out(
    const unsigned short* __restrict__ qf, const unsigned short* __restrict__ kf,
    const unsigned short* __restrict__ vf, const unsigned short* __restrict__ kvb,
    const unsigned short* __restrict__ ksb, unsigned short* __restrict__ attn)
{
    constexpr int LK = 72;    // K stride (64+8)
    constexpr int LV = 136;   // Vt & S stride (128+8)
    __shared__ unsigned short Ks[128 * LK];   // 18.0 KB
    __shared__ unsigned short Vt[64 * LV];    // 17.0 KB
    __shared__ unsigned short Ss[128 * LV];   // 34.0 KB

    int t = threadIdx.x, lane = t & 63, w = t >> 6;
    int bid = blockIdx.x;
    int bh = bid >> 5, c = bid & 31;
    const unsigned short* qp = qf + (size_t)bid * CHK * E_;
    const unsigned short* kp = kf + (size_t)bid * CHK * E_;
    const unsigned short* vp = vf + (size_t)bid * CHK * E_;
    const unsigned short* kvp = kvb + (size_t)bid * 4096;   // [f][e]

    int lr = lane & 15, lg = lane >> 4;
    const int jsel[2] = {w, 7 - w};

    // Q frags for this wave's two row-blocks (global, coalesced 64B rows)
    bf16x8 aq[2][2];
#pragma unroll
    for (int mi = 0; mi < 2; ++mi)
#pragma unroll
        for (int ks = 0; ks < 2; ++ks)
            aq[mi][ks] = *(const bf16x8*)(qp + (jsel[mi]*16 + lr) * 64 + ks*32 + lg*8);

#pragma unroll
    for (int it = 0; it < 4; ++it) {
        int s = it * 256 + t;
        int r = s >> 3, e0 = (s & 7) << 3;
        uint4 kv = *(const uint4*)(kp + s * 8);
        uint4 vv = *(const uint4*)(vp + s * 8);
        *(uint4*)&Ks[r * LK + e0] = kv;
        unsigned int vw[4] = {vv.x, vv.y, vv.z, vv.w};
#pragma unroll
        for (int jw = 0; jw < 4; ++jw) {
            Vt[(e0 + 2*jw    ) * LV + r] = (unsigned short)(vw[jw] & 0xFFFF);
            Vt[(e0 + 2*jw + 1) * LV + r] = (unsigned short)(vw[jw] >> 16);
        }
    }
    // den B-rows in regs: only lr==0 lanes hold data (b-row 64)
    bf16x8 zfrag = {0,0,0,0,0,0,0,0};
    bf16x8 bone = zfrag, bks[2] = {zfrag, zfrag};
    if (lr == 0) {
#pragma unroll
        for (int j = 0; j < 8; ++j) bone[j] = (short)0x3F80;
        bks[0] = *(const bf16x8*)&ksb[(size_t)bid * 64 + lg*8];
        bks[1] = *(const bf16x8*)&ksb[(size_t)bid * 64 + 32 + lg*8];
    }
    __syncthreads();

    // S-phase: wave w writes row-blocks jsel[0..1]
#pragma unroll
    for (int mi = 0; mi < 2; ++mi) {
        int j = jsel[mi];
        int rbase = j * 16;
        int jbmax = j | 1;                 // PV reads cols up to block (j|1)
        for (int jb = 0; jb <= jbmax; ++jb) {
            if (jb <= j) {
                f32x4 sacc = {};
                bf16x8 b0 = *(const bf16x8*)&Ks[(jb*16 + lr) * LK + lg*8];
                bf16x8 b1 = *(const bf16x8*)&Ks[(jb*16 + lr) * LK + 32 + lg*8];
                sacc = __builtin_amdgcn_mfma_f32_16x16x32_bf16(aq[mi][0], b0, sacc, 0, 0, 0);
                sacc = __builtin_amdgcn_mfma_f32_16x16x32_bf16(aq[mi][1], b1, sacc, 0, 0, 0);
#pragma unroll
                for (int q = 0; q < 4; ++q) {
                    int r = rbase + lg*4 + q;
                    int jj = jb*16 + lr;
                    Ss[r * LV + jj] = (jj <= r) ? f2bf(sacc[q]) : (unsigned short)0;
                }
            } else {
#pragma unroll
                for (int q = 0; q < 4; ++q) {
                    int r = rbase + lg*4 + q;
                    Ss[r * LV + jb*16 + lr] = 0;
                }
            }
        }
    }
    // no barrier needed: each wave reads only its own S rows below

    f32x4 oacc[2][5] = {};
#pragma unroll
    for (int mi = 0; mi < 2; ++mi) {
        int j = jsel[mi];
        int rbase = j * 16;
        // inter-chunk: Q @ KV_state (K-dim 64); B frags from global [f][e]
#pragma unroll
        for (int ks = 0; ks < 2; ++ks) {
            bf16x8 a = aq[mi][ks];
#pragma unroll
            for (int n = 0; n < 4; ++n) {
                bf16x8 b = *(const bf16x8*)&kvp[(n*16 + lr) * 64 + ks*32 + lg*8];
                oacc[mi][n] = __builtin_amdgcn_mfma_f32_16x16x32_bf16(a, b, oacc[mi][n], 0, 0, 0);
            }
            oacc[mi][4] = __builtin_amdgcn_mfma_f32_16x16x32_bf16(a, bks[ks], oacc[mi][4], 0, 0, 0);
        }
        // intra-chunk: S @ V  (k-blocks ks <= j>>1 nonzero)
        for (int ks = 0; ks <= (j >> 1); ++ks) {
            bf16x8 a = *(const bf16x8*)&Ss[(rbase + lr) * LV + ks*32 + lg*8];
#pragma unroll
            for (int n = 0; n < 4; ++n) {
                bf16x8 b = *(const bf16x8*)&Vt[(n*16 + lr) * LV + ks*32 + lg*8];
                oacc[mi][n] = __builtin_amdgcn_mfma_f32_16x16x32_bf16(a, b, oacc[mi][n], 0, 0, 0);
            }
            oacc[mi][4] = __builtin_amdgcn_mfma_f32_16x16x32_bf16(a, bone, oacc[mi][4], 0, 0, 0);
        }
    }

    // den broadcast (col 64 lives in lanes with lr==0) + normalize + store
    int b_idx = bh >> 4, h_idx = bh & 15;
#pragma unroll
    for (int mi = 0; mi < 2; ++mi) {
        int rbase = jsel[mi] * 16;
        float den[4];
#pragma unroll
        for (int q = 0; q < 4; ++q)
            den[q] = __shfl(oacc[mi][4][q], lane & 48, 64) + EPS_DEN;
#pragma unroll
        for (int n = 0; n < 4; ++n) {
#pragma unroll
            for (int q = 0; q < 4; ++q) {
                int r = rbase + lg*4 + q;
                int lpos = c * CHK + r;
                int col = n*16 + lr;
                size_t dst = ((size_t)b_idx * L_ + lpos) * D_ + h_idx * 64 + col;
                attn[dst] = f2bf(oacc[mi][n][q] / den[q]);
            }
        }
    }
}

// ---------------- launcher ----------------

extern "C" void kernel_launch(void* const* d_in, const int* in_sizes, int n_in,
                              void* d_out, int out_size, void* d_ws, size_t ws_size,
                              hipStream_t stream)
{
    const float* x    = (const float*)d_in[0];
    const float* Wqkv = (const float*)d_in[1];
    const float* bqkv = (const float*)d_in[2];
    const float* Wout = (const float*)d_in[3];
    const float* bout = (const float*)d_in[4];
    float* out = (float*)d_out;

    char* ws = (char*)d_ws;
    size_t off = 0;
    auto alloc = [&](size_t bytes) { void* p = ws + off; off += (bytes + 255) & ~(size_t)255; return p; };
    unsigned short* xb  = (unsigned short*)alloc((size_t)M_ * D_ * 2);
    unsigned short* WqT = (unsigned short*)alloc((size_t)N1_ * D_ * 2);
    unsigned short* WoT = (unsigned short*)alloc((size_t)D_ * D_ * 2);
    unsigned short* qfb = (unsigned short*)alloc((size_t)M_ * D_ * 2);
    unsigned short* kfb = (unsigned short*)alloc((size_t)M_ * D_ * 2);
    unsigned short* vfb = (unsigned short*)alloc((size_t)M_ * D_ * 2);
    float* kvw = (float*)alloc((size_t)BH * NC * E_ * E_ * 4);
    float* ksw = (float*)alloc((size_t)BH * NC * E_ * 4);
    unsigned short* kvb = (unsigned short*)alloc((size_t)BH * NC * E_ * E_ * 2);
    unsigned short* ksb = (unsigned short*)alloc((size_t)BH * NC * E_ * 2);
    unsigned short* attn = xb;   // alias: x_bf16 is dead after gemm<0>

    cvt_x<<<(M_ * D_ / 4) / 256, 256, 0, stream>>>(x, xb);
    transp_w2<<<dim3(N1_ / 32, D_ / 32, 2), 256, 0, stream>>>(Wqkv, Wout, WqT, WoT);

    gemm256<0, D_, N1_><<<dim3(N1_ / 256, M_ / 256), 512, 0, stream>>>(
        xb, WqT, bqkv, nullptr, qfb, kfb, vfb);

    chunk_kv<<<BH * NC, 256, 0, stream>>>(kfb, vfb, kvw, ksw);
    prefix_kv<<<dim3(16, BH), 256, 0, stream>>>(kvw, ksw, kvb, ksb);
    attn_out<<<BH * NC, 256, 0, stream>>>(qfb, kfb, vfb, kvb, ksb, attn);

    gemm256<1, D_, D_><<<dim3(D_ / 256, M_ / 256), 512, 0, stream>>>(
        attn, WoT, bout, out, nullptr, nullptr, nullptr);
}

// Round 9
// 239.875 us; speedup vs baseline: 1.4915x; 1.0092x over previous
//
#include <hip/hip_runtime.h>
#include <hip/hip_bf16.h>
#include <stdint.h>

#define B_ 4
#define L_ 4096
#define D_ 1024
#define H_ 16
#define E_ 64
#define M_ (B_*L_)       // 16384 rows
#define N1_ (3*D_)       // 3072
#define CHK 128
#define NC (L_/CHK)      // 32
#define BH (B_*H_)       // 64

#define EPS_FEAT 1.0001f
#define EPS_DEN 1e-6f

typedef __attribute__((ext_vector_type(4))) float f32x4;
typedef __attribute__((ext_vector_type(8))) short bf16x8;

__device__ __forceinline__ unsigned short f2bf(float x) {
    union { float f; unsigned int u; } v; v.f = x;
    unsigned int r = v.u + 0x7FFFu + ((v.u >> 16) & 1u);
    return (unsigned short)(r >> 16);
}

// async global->LDS, 16B per lane. LDS dest = wave-uniform base + lane*16.
__device__ __forceinline__ void gload_lds16(const unsigned short* g, unsigned short* l) {
    __builtin_amdgcn_global_load_lds(
        (const __attribute__((address_space(1))) unsigned int*)(const void*)g,
        (__attribute__((address_space(3))) unsigned int*)(void*)l,
        16, 0, 0);
}

// ---------------- prep: x->bf16 (blocks 0..16383) + both W transposes ----------------

__global__ __launch_bounds__(256) void prep(const float* __restrict__ x,
                                            const float* __restrict__ W0,
                                            const float* __restrict__ W1,
                                            unsigned short* __restrict__ xb,
                                            unsigned short* __restrict__ T0,
                                            unsigned short* __restrict__ T1) {
    __shared__ float tile[32][33];
    int bid = blockIdx.x, t = threadIdx.x;
    if (bid < 16384) {
        int i4 = bid * 256 + t;
        float4 v = ((const float4*)x)[i4];
        unsigned int lo = (unsigned int)f2bf(v.x) | ((unsigned int)f2bf(v.y) << 16);
        unsigned int hi = (unsigned int)f2bf(v.z) | ((unsigned int)f2bf(v.w) << 16);
        ((uint2*)xb)[i4] = make_uint2(lo, hi);
        return;
    }
    const float* W; unsigned short* WT; int N, nb, kb;
    if (bid < 16384 + 3072) {
        int idx = bid - 16384;             // Wqkv: 96 x 32
        W = W0; WT = T0; N = N1_;
        nb = (idx % 96) * 32; kb = (idx / 96) * 32;
    } else {
        int idx = bid - 16384 - 3072;      // Wout: 32 x 32
        W = W1; WT = T1; N = D_;
        nb = (idx % 32) * 32; kb = (idx / 32) * 32;
    }
    int tx = t & 31, ty = t >> 5;          // ty 0..7
#pragma unroll
    for (int j = 0; j < 4; ++j)
        tile[ty + 8*j][tx] = W[(size_t)(kb + ty + 8*j) * N + nb + tx];
    __syncthreads();
#pragma unroll
    for (int j = 0; j < 4; ++j) {
        int nl = ty + 8*j;
        WT[(size_t)(nb + nl) * D_ + kb + tx] = f2bf(tile[tx][nl]);
    }
}

// ---------------- 256x256 pipelined GEMM (A bf16 MxK, BT bf16 NxK) ----------------
// BK=64, 2-buffer dbuf (128KB), 2 phases/K-tile (32 MFMA each), ONE barrier
// per phase (pre-MFMA), vmcnt(4) once per tile, row&7 XOR swizzle.
// Stage slots: p1: T+1.A0+A1 (other buffer; last readers tile T-1 p1/p2,
//   >=2 barriers separation). p2: T+2.B0+B1 (current buffer; B last read at
//   p1 - reads issued before p1-pre barrier, awaited at p1-pre lgkm; stage
//   LDS-write lands at HBM-return >=300cyc after issue -> safe WAR margin).
// vmcnt ledger: at tile start outstanding = T+1.B(4). During T: +T+1.A(4),
//   +T+2.B(4) = 12. End vmcnt(4) retires T+1.B,T+1.A -> T+1 landed.

template<int MODE, int KDIM, int NDIM>
__global__ __launch_bounds__(512, 2) void gemm256(
    const unsigned short* __restrict__ A,
    const unsigned short* __restrict__ BT,
    const float* __restrict__ bias,
    float* __restrict__ outF,
    unsigned short* __restrict__ qf,
    unsigned short* __restrict__ kf,
    unsigned short* __restrict__ vf)
{
    __shared__ __align__(16) unsigned short smem[65536];   // 2 x (A 32KB | B 32KB)

    const int t = threadIdx.x, lane = t & 63, w = t >> 6;
    const int wr = w >> 2, wc = w & 3;                      // 2 x 4 wave grid

    // XCD-chunked bijective swizzle (nwg % 8 == 0 for both modes)
    const int nwgx = NDIM / 256;
    const int nwg = nwgx * (M_ / 256);
    const int bid0 = blockIdx.y * nwgx + blockIdx.x;
    const int swz = (bid0 & 7) * (nwg >> 3) + (bid0 >> 3);
    const int m0 = (swz / nwgx) * 256, n0 = (swz % nwgx) * 256;
    const int lr = lane & 15, lg = lane >> 4;

    auto stage = [&](int T, int ab, int h) {
        unsigned short* base = smem + (T & 1) * 32768 + ab * 16384 + h * 8192;
        const unsigned short* src = ab ? BT : A;
        const int boff = (ab ? n0 : m0) + h * 128;
        const int kt = T * 64;
#pragma unroll
        for (int i = 0; i < 2; ++i) {
            int c = i * 512 + t;
            int rowl = c >> 3, s = c & 7;
            int col = ((s ^ (rowl & 7)) << 3);
            gload_lds16(src + (size_t)(boff + rowl) * KDIM + kt + col, &base[c * 8]);
        }
    };

    f32x4 acc[8][4] = {};

    auto rdA = [&](const unsigned short* Ab, int m, int ks) {
        int row = wr * 128 + m * 16 + lr;
        int slot = (ks * 4 + lg) ^ (row & 7);
        return *(const bf16x8*)&Ab[row * 64 + slot * 8];
    };
    auto rdB = [&](const unsigned short* Bb, int n, int ks) {
        int row = wc * 64 + n * 16 + lr;
        int slot = (ks * 4 + lg) ^ (row & 7);
        return *(const bf16x8*)&Bb[row * 64 + slot * 8];
    };

#define PHASE_PRE() \
    __builtin_amdgcn_s_barrier(); \
    asm volatile("s_waitcnt lgkmcnt(0)" ::: "memory"); \
    __builtin_amdgcn_sched_barrier(0); \
    __builtin_amdgcn_s_setprio(1);
#define PHASE_POST() \
    __builtin_amdgcn_s_setprio(0);

    auto tile = [&](int T, bool s1, bool s2) {
        const unsigned short* Ab = smem + (T & 1) * 32768;
        const unsigned short* Bb = Ab + 16384;
        bf16x8 a0[4][2], a1[4][2], bq[4][2];
        // ---- p1: m0-3 x all n (32 MFMA); stage T+1.A0+A1 ----
#pragma unroll
        for (int m = 0; m < 4; ++m) { a0[m][0] = rdA(Ab, m, 0); a0[m][1] = rdA(Ab, m, 1); }
#pragma unroll
        for (int n = 0; n < 4; ++n) { bq[n][0] = rdB(Bb, n, 0); bq[n][1] = rdB(Bb, n, 1); }
        if (s1) { stage(T + 1, 0, 0); stage(T + 1, 0, 1); }
        PHASE_PRE();
#pragma unroll
        for (int m = 0; m < 4; ++m)
#pragma unroll
            for (int n = 0; n < 4; ++n) {
                acc[m][n] = __builtin_amdgcn_mfma_f32_16x16x32_bf16(a0[m][0], bq[n][0], acc[m][n], 0, 0, 0);
                acc[m][n] = __builtin_amdgcn_mfma_f32_16x16x32_bf16(a0[m][1], bq[n][1], acc[m][n], 0, 0, 0);
            }
        PHASE_POST();
        // ---- p2: m4-7 x all n (32 MFMA); stage T+2.B0+B1 ----
#pragma unroll
        for (int m = 0; m < 4; ++m) { a1[m][0] = rdA(Ab, 4+m, 0); a1[m][1] = rdA(Ab, 4+m, 1); }
        if (s2) { stage(T + 2, 1, 0); stage(T + 2, 1, 1); }
        PHASE_PRE();
#pragma unroll
        for (int m = 0; m < 4; ++m)
#pragma unroll
            for (int n = 0; n < 4; ++n) {
                acc[4+m][n] = __builtin_amdgcn_mfma_f32_16x16x32_bf16(a1[m][0], bq[n][0], acc[4+m][n], 0, 0, 0);
                acc[4+m][n] = __builtin_amdgcn_mfma_f32_16x16x32_bf16(a1[m][1], bq[n][1], acc[4+m][n], 0, 0, 0);
            }
        PHASE_POST();
        // end-of-tile vmcnt + barrier placed by caller
    };

    constexpr int NT = KDIM / 64;                 // 16
    // prologue: T0 all 4 halves + T1.B0/B1 (T1.A staged during T0 p1)
    stage(0, 0, 0); stage(0, 0, 1); stage(0, 1, 0); stage(0, 1, 1);
    stage(1, 1, 0); stage(1, 1, 1);
    asm volatile("s_waitcnt vmcnt(4)" ::: "memory");     // tile 0 landed
    __builtin_amdgcn_s_barrier();
    __builtin_amdgcn_sched_barrier(0);

    for (int T = 0; T < NT - 2; ++T) {
        tile(T, true, true);
        asm volatile("s_waitcnt vmcnt(4)" ::: "memory"); // T+1 fully landed
        __builtin_amdgcn_s_barrier();
        __builtin_amdgcn_sched_barrier(0);
    }
    tile(NT - 2, true, false);                           // stages NT-1.A0/A1 only
    asm volatile("s_waitcnt vmcnt(0)" ::: "memory");     // NT-1 fully landed
    __builtin_amdgcn_s_barrier();
    __builtin_amdgcn_sched_barrier(0);
    tile(NT - 1, false, false);
    __syncthreads();                                     // LDS reuse below

    // ---------------- epilogues (LDS-routed, coalesced stores) ----------------
    if (MODE == 0) {
        unsigned short* cbf = smem;                      // [128][264] bf16 per pass
        const bool isQ = (n0 < D_), isK = (n0 >= D_ && n0 < 2*D_);
        const float scale = isQ ? 0.125f : 1.0f;
        unsigned short* buf = isQ ? qf : (isK ? kf : vf);
        const int b = m0 >> 12, l0 = m0 & 4095;
        const int h0 = (n0 & 1023) >> 6;
#pragma unroll
        for (int p = 0; p < 2; ++p) {
            if (wr == p) {
#pragma unroll
                for (int n = 0; n < 4; ++n) {
                    int cl = wc*64 + n*16 + lr;
                    float bv = bias[n0 + cl];
#pragma unroll
                    for (int m = 0; m < 8; ++m)
#pragma unroll
                        for (int q = 0; q < 4; ++q) {
                            int rl = m*16 + lg*4 + q;
                            float val = (acc[m][n][q] + bv) * scale;
                            float fv = (isQ || isK)
                                       ? ((val > 0.f ? val : __expf(val) - 1.f) + EPS_FEAT)
                                       : val;
                            cbf[rl * 264 + cl] = f2bf(fv);
                        }
                }
            }
            __syncthreads();
#pragma unroll
            for (int hh = 0; hh < 4; ++hh) {
                unsigned short* dst = buf + (((size_t)(b * H_ + h0 + hh)) * L_ + l0 + p*128) * E_;
#pragma unroll
                for (int i = 0; i < 2; ++i) {
                    int c = i*512 + t, row = c >> 3, ch = c & 7;
                    uint4 v = *(const uint4*)&cbf[row * 264 + hh*64 + ch*8];
                    *(uint4*)&dst[row * 64 + ch*8] = v;
                }
            }
            __syncthreads();
        }
    } else {
        float* cfl = (float*)smem;                       // [64][260] f32 per pass
#pragma unroll
        for (int p = 0; p < 4; ++p) {
            if (wr == (p >> 1)) {
                int mbase = (p & 1) * 4;
#pragma unroll
                for (int n = 0; n < 4; ++n) {
                    int cl = wc*64 + n*16 + lr;
                    float bv = bias[n0 + cl];
#pragma unroll
                    for (int mm = 0; mm < 4; ++mm)
#pragma unroll
                        for (int q = 0; q < 4; ++q) {
                            int rl = mm*16 + lg*4 + q;
                            cfl[rl * 260 + cl] = acc[mbase + mm][n][q] + bv;
                        }
                }
            }
            __syncthreads();
#pragma unroll
            for (int i = 0; i < 8; ++i) {
                int c = i*512 + t, row = c >> 6, ch = c & 63;
                float4 v = *(const float4*)&cfl[row * 260 + ch*4];
                *(float4*)&outF[(size_t)(m0 + p*64 + row) * NDIM + n0 + ch*4] = v;
            }
            __syncthreads();
        }
    }
#undef PHASE_PRE
#undef PHASE_POST
}

// ---------------- chunk KV (TRANSPOSED state): KVT_c[f][e] = sum_l V[l][f] K[l][e] ----------------
// ksum via Vt ones-row (row 64) as A-operand on wave 0.

__global__ __launch_bounds__(256) void chunk_kv(
    const unsigned short* __restrict__ kf, const unsigned short* __restrict__ vf,
    float* __restrict__ kvout, float* __restrict__ ksout)
{
    constexpr int LDK = 136;                 // 128 + 8 pad
    __shared__ unsigned short Kt[64 * LDK];  // K^T : [e][l]
    __shared__ unsigned short Vt[80 * LDK];  // V^T : [f][l], row 64 = ones (ksum trick)

    int t = threadIdx.x, lane = t & 63, w = t >> 6;
    int bid = blockIdx.x;                    // bh*NC + c
    const unsigned short* kp = kf + (size_t)bid * CHK * E_;
    const unsigned short* vp = vf + (size_t)bid * CHK * E_;

#pragma unroll
    for (int it = 0; it < 4; ++it) {
        int s = it * 256 + t;                // 0..1023  (16B granules of 128x64)
        int rl = s >> 3, e0 = (s & 7) << 3;
        uint4 kv8 = *(const uint4*)(kp + s * 8);
        uint4 vv8 = *(const uint4*)(vp + s * 8);
        unsigned int kw[4] = {kv8.x, kv8.y, kv8.z, kv8.w};
        unsigned int vw[4] = {vv8.x, vv8.y, vv8.z, vv8.w};
#pragma unroll
        for (int jw = 0; jw < 4; ++jw) {
            Kt[(e0 + 2*jw    ) * LDK + rl] = (unsigned short)(kw[jw] & 0xFFFF);
            Kt[(e0 + 2*jw + 1) * LDK + rl] = (unsigned short)(kw[jw] >> 16);
            Vt[(e0 + 2*jw    ) * LDK + rl] = (unsigned short)(vw[jw] & 0xFFFF);
            Vt[(e0 + 2*jw + 1) * LDK + rl] = (unsigned short)(vw[jw] >> 16);
        }
    }
    if (t < 128) Vt[64 * LDK + t] = 0x3F80;  // bf16 1.0
    for (int i = t; i < 15 * LDK; i += 256) Vt[65 * LDK + i] = 0;
    __syncthreads();

    int lr = lane & 15, lg = lane >> 4;
    f32x4 acc[4] = {};
    f32x4 accE[4] = {};
#pragma unroll
    for (int ks = 0; ks < 4; ++ks) {
        bf16x8 a = *(const bf16x8*)&Vt[(w*16 + lr) * LDK + ks*32 + lg*8];
#pragma unroll
        for (int n = 0; n < 4; ++n) {
            bf16x8 b = *(const bf16x8*)&Kt[(n*16 + lr) * LDK + ks*32 + lg*8];
            acc[n] = __builtin_amdgcn_mfma_f32_16x16x32_bf16(a, b, acc[n], 0, 0, 0);
        }
    }
    if (w == 0) {
#pragma unroll
        for (int ks = 0; ks < 4; ++ks) {
            bf16x8 a = *(const bf16x8*)&Vt[(64 + lr) * LDK + ks*32 + lg*8];
#pragma unroll
            for (int n = 0; n < 4; ++n) {
                bf16x8 b = *(const bf16x8*)&Kt[(n*16 + lr) * LDK + ks*32 + lg*8];
                accE[n] = __builtin_amdgcn_mfma_f32_16x16x32_bf16(a, b, accE[n], 0, 0, 0);
            }
        }
    }
    float* kvo = kvout + (size_t)bid * E_ * E_;   // [f][e]
#pragma unroll
    for (int n = 0; n < 4; ++n)
#pragma unroll
        for (int q = 0; q < 4; ++q) {
            int f = w*16 + lg*4 + q, e = n*16 + lr;
            kvo[f * 64 + e] = acc[n][q];
        }
    if (w == 0 && lg == 0) {
#pragma unroll
        for (int n = 0; n < 4; ++n)
            ksout[(size_t)bid * 64 + n*16 + lr] = accE[n][0];   // row 64 = ksum
    }
}

// ---------------- exclusive prefix over chunks (per bh), bf16 output, float4 ----------------

__global__ __launch_bounds__(256) void prefix_kv(
    const float4* __restrict__ kv, const float* __restrict__ ks,
    uint2* __restrict__ kvb, unsigned short* __restrict__ ksb)
{
    int bh = blockIdx.y, part = blockIdx.x, t = threadIdx.x;
    int idx = part * 256 + t;                 // float4 index within 1024/chunk
    float4 st = make_float4(0.f, 0.f, 0.f, 0.f);
    for (int c = 0; c < NC; ++c) {
        float4 tmp = kv[((size_t)bh * NC + c) * 1024 + idx];
        kvb[((size_t)bh * NC + c) * 1024 + idx] = make_uint2(
            (unsigned int)f2bf(st.x) | ((unsigned int)f2bf(st.y) << 16),
            (unsigned int)f2bf(st.z) | ((unsigned int)f2bf(st.w) << 16));
        st.x += tmp.x; st.y += tmp.y; st.z += tmp.z; st.w += tmp.w;
    }
    if (part == 0 && t < 64) {
        float s0 = 0.f;
        for (int c = 0; c < NC; ++c) {
            float tmp = ks[((size_t)bh * NC + c) * 64 + t];
            ksb[((size_t)bh * NC + c) * 64 + t] = f2bf(s0);
            s0 += tmp;
        }
    }
}

// ---------------- attention output per (bh, chunk) ----------------
// LDS 69KB -> 2 blocks/CU. Wave w owns row-blocks {w, 7-w} (balanced causal).

__global__ __launch_bounds__(256, 2) void attn_out(
    const unsigned short* __restrict__ qf, const unsigned short* __restrict__ kf,
    const unsigned short* __restrict__ vf, const unsigned short* __restrict__ kvb,
    const unsigned short* __restrict__ ksb, unsigned short* __restrict__ attn)
{
    constexpr int LK = 72;    // K stride (64+8)
    constexpr int LV = 136;   // Vt & S stride (128+8)
    __shared__ unsigned short Ks[128 * LK];   // 18.0 KB
    __shared__ unsigned short Vt[64 * LV];    // 17.0 KB
    __shared__ unsigned short Ss[128 * LV];   // 34.0 KB

    int t = threadIdx.x, lane = t & 63, w = t >> 6;
    int bid = blockIdx.x;
    int bh = bid >> 5, c = bid & 31;
    const unsigned short* qp = qf + (size_t)bid * CHK * E_;
    const unsigned short* kp = kf + (size_t)bid * CHK * E_;
    const unsigned short* vp = vf + (size_t)bid * CHK * E_;
    const unsigned short* kvp = kvb + (size_t)bid * 4096;   // [f][e]

    int lr = lane & 15, lg = lane >> 4;
    const int jsel[2] = {w, 7 - w};

    // Q frags for this wave's two row-blocks (global, coalesced 64B rows)
    bf16x8 aq[2][2];
#pragma unroll
    for (int mi = 0; mi < 2; ++mi)
#pragma unroll
        for (int ks = 0; ks < 2; ++ks)
            aq[mi][ks] = *(const bf16x8*)(qp + (jsel[mi]*16 + lr) * 64 + ks*32 + lg*8);

#pragma unroll
    for (int it = 0; it < 4; ++it) {
        int s = it * 256 + t;
        int r = s >> 3, e0 = (s & 7) << 3;
        uint4 kv = *(const uint4*)(kp + s * 8);
        uint4 vv = *(const uint4*)(vp + s * 8);
        *(uint4*)&Ks[r * LK + e0] = kv;
        unsigned int vw[4] = {vv.x, vv.y, vv.z, vv.w};
#pragma unroll
        for (int jw = 0; jw < 4; ++jw) {
            Vt[(e0 + 2*jw    ) * LV + r] = (unsigned short)(vw[jw] & 0xFFFF);
            Vt[(e0 + 2*jw + 1) * LV + r] = (unsigned short)(vw[jw] >> 16);
        }
    }
    // den B-rows in regs: only lr==0 lanes hold data (b-row 64)
    bf16x8 zfrag = {0,0,0,0,0,0,0,0};
    bf16x8 bone = zfrag, bks[2] = {zfrag, zfrag};
    if (lr == 0) {
#pragma unroll
        for (int j = 0; j < 8; ++j) bone[j] = (short)0x3F80;
        bks[0] = *(const bf16x8*)&ksb[(size_t)bid * 64 + lg*8];
        bks[1] = *(const bf16x8*)&ksb[(size_t)bid * 64 + 32 + lg*8];
    }
    __syncthreads();

    // S-phase: wave w writes row-blocks jsel[0..1]
#pragma unroll
    for (int mi = 0; mi < 2; ++mi) {
        int j = jsel[mi];
        int rbase = j * 16;
        int jbmax = j | 1;                 // PV reads cols up to block (j|1)
        for (int jb = 0; jb <= jbmax; ++jb) {
            if (jb <= j) {
                f32x4 sacc = {};
                bf16x8 b0 = *(const bf16x8*)&Ks[(jb*16 + lr) * LK + lg*8];
                bf16x8 b1 = *(const bf16x8*)&Ks[(jb*16 + lr) * LK + 32 + lg*8];
                sacc = __builtin_amdgcn_mfma_f32_16x16x32_bf16(aq[mi][0], b0, sacc, 0, 0, 0);
                sacc = __builtin_amdgcn_mfma_f32_16x16x32_bf16(aq[mi][1], b1, sacc, 0, 0, 0);
#pragma unroll
                for (int q = 0; q < 4; ++q) {
                    int r = rbase + lg*4 + q;
                    int jj = jb*16 + lr;
                    Ss[r * LV + jj] = (jj <= r) ? f2bf(sacc[q]) : (unsigned short)0;
                }
            } else {
#pragma unroll
                for (int q = 0; q < 4; ++q) {
                    int r = rbase + lg*4 + q;
                    Ss[r * LV + jb*16 + lr] = 0;
                }
            }
        }
    }
    // no barrier needed: each wave reads only its own S rows below

    f32x4 oacc[2][5] = {};
#pragma unroll
    for (int mi = 0; mi < 2; ++mi) {
        int j = jsel[mi];
        int rbase = j * 16;
        // inter-chunk: Q @ KV_state (K-dim 64); B frags from global [f][e]
#pragma unroll
        for (int ks = 0; ks < 2; ++ks) {
            bf16x8 a = aq[mi][ks];
#pragma unroll
            for (int n = 0; n < 4; ++n) {
                bf16x8 b = *(const bf16x8*)&kvp[(n*16 + lr) * 64 + ks*32 + lg*8];
                oacc[mi][n] = __builtin_amdgcn_mfma_f32_16x16x32_bf16(a, b, oacc[mi][n], 0, 0, 0);
            }
            oacc[mi][4] = __builtin_amdgcn_mfma_f32_16x16x32_bf16(a, bks[ks], oacc[mi][4], 0, 0, 0);
        }
        // intra-chunk: S @ V  (k-blocks ks <= j>>1 nonzero)
        for (int ks = 0; ks <= (j >> 1); ++ks) {
            bf16x8 a = *(const bf16x8*)&Ss[(rbase + lr) * LV + ks*32 + lg*8];
#pragma unroll
            for (int n = 0; n < 4; ++n) {
                bf16x8 b = *(const bf16x8*)&Vt[(n*16 + lr) * LV + ks*32 + lg*8];
                oacc[mi][n] = __builtin_amdgcn_mfma_f32_16x16x32_bf16(a, b, oacc[mi][n], 0, 0, 0);
            }
            oacc[mi][4] = __builtin_amdgcn_mfma_f32_16x16x32_bf16(a, bone, oacc[mi][4], 0, 0, 0);
        }
    }

    // den broadcast (col 64 lives in lanes with lr==0) + normalize + store
    int b_idx = bh >> 4, h_idx = bh & 15;
#pragma unroll
    for (int mi = 0; mi < 2; ++mi) {
        int rbase = jsel[mi] * 16;
        float den[4];
#pragma unroll
        for (int q = 0; q < 4; ++q)
            den[q] = __shfl(oacc[mi][4][q], lane & 48, 64) + EPS_DEN;
#pragma unroll
        for (int n = 0; n < 4; ++n) {
#pragma unroll
            for (int q = 0; q < 4; ++q) {
                int r = rbase + lg*4 + q;
                int lpos = c * CHK + r;
                int col = n*16 + lr;
                size_t dst = ((size_t)b_idx * L_ + lpos) * D_ + h_idx * 64 + col;
                attn[dst] = f2bf(oacc[mi][n][q] / den[q]);
            }
        }
    }
}

// ---------------- launcher ----------------

extern "C" void kernel_launch(void* const* d_in, const int* in_sizes, int n_in,
                              void* d_out, int out_size, void* d_ws, size_t ws_size,
                              hipStream_t stream)
{
    const float* x    = (const float*)d_in[0];
    const float* Wqkv = (const float*)d_in[1];
    const float* bqkv = (const float*)d_in[2];
    const float* Wout = (const float*)d_in[3];
    const float* bout = (const float*)d_in[4];
    float* out = (float*)d_out;

    char* ws = (char*)d_ws;
    size_t off = 0;
    auto alloc = [&](size_t bytes) { void* p = ws + off; off += (bytes + 255) & ~(size_t)255; return p; };
    unsigned short* xb  = (unsigned short*)alloc((size_t)M_ * D_ * 2);
    unsigned short* WqT = (unsigned short*)alloc((size_t)N1_ * D_ * 2);
    unsigned short* WoT = (unsigned short*)alloc((size_t)D_ * D_ * 2);
    unsigned short* qfb = (unsigned short*)alloc((size_t)M_ * D_ * 2);
    unsigned short* kfb = (unsigned short*)alloc((size_t)M_ * D_ * 2);
    unsigned short* vfb = (unsigned short*)alloc((size_t)M_ * D_ * 2);
    float* kvw = (float*)alloc((size_t)BH * NC * E_ * E_ * 4);
    float* ksw = (float*)alloc((size_t)BH * NC * E_ * 4);
    unsigned short* kvb = (unsigned short*)alloc((size_t)BH * NC * E_ * E_ * 2);
    unsigned short* ksb = (unsigned short*)alloc((size_t)BH * NC * E_ * 2);
    unsigned short* attn = xb;   // alias: x_bf16 is dead after gemm<0>

    prep<<<16384 + 3072 + 1024, 256, 0, stream>>>(x, Wqkv, Wout, xb, WqT, WoT);

    gemm256<0, D_, N1_><<<dim3(N1_ / 256, M_ / 256), 512, 0, stream>>>(
        xb, WqT, bqkv, nullptr, qfb, kfb, vfb);

    chunk_kv<<<BH * NC, 256, 0, stream>>>(kfb, vfb, kvw, ksw);
    prefix_kv<<<dim3(4, BH), 256, 0, stream>>>((const float4*)kvw, ksw, (uint2*)kvb, ksb);
    attn_out<<<BH * NC, 256, 0, stream>>>(qfb, kfb, vfb, kvb, ksb, attn);

    gemm256<1, D_, D_><<<dim3(D_ / 256, M_ / 256), 512, 0, stream>>>(
        attn, WoT, bout, out, nullptr, nullptr, nullptr);
}